// Round 2
// baseline (350.001 us; speedup 1.0000x reference)
//
#include <hip/hip_runtime.h>
#include <cstddef>

typedef __bf16 bf16;
typedef __bf16 bf16x8 __attribute__((ext_vector_type(8)));
typedef float  f32x4  __attribute__((ext_vector_type(4)));

#define MFMA16(a, b, c) __builtin_amdgcn_mfma_f32_16x16x32_bf16((a), (b), (c), 0, 0, 0)

// ---------------- constants ----------------
#define BB 8
#define CC 2048
#define DD 128
#define JJN 128

// ws layout (bytes)
#define WS_VT    ((size_t)0)          // bf16 [8][128][2048]  (V transposed)
#define WS_OATT  ((size_t)4194304)    // bf16 [8][2048][128]
#define WS_OPS16 ((size_t)8388608)    // bf16 [8][2048][128]  (ops cast to bf16)
#define WS_SQF   ((size_t)12582912)   // f32  [8][2048]
#define WS_SKF   ((size_t)12648448)   // f32  [8][2048]
#define WS_G1T   ((size_t)12713984)   // bf16 [128][128] (transposed: [e][d])
#define WS_G2T   ((size_t)12746752)
#define WS_G3T   ((size_t)12779520)
#define WS_WCT   ((size_t)12812288)
#define WS_GBT   ((size_t)12845056)
#define WS_GET   ((size_t)12877824)
#define WS_UQK   ((size_t)12910592)   // bf16 [2][128]  (uq row, uk row)
#define WS_BBM   ((size_t)12911104)   // f32 [128]
#define WS_BBB   ((size_t)12911616)   // f32 [128]
#define WS_BBE   ((size_t)12912128)   // f32 [128]
#define WS_SC    ((size_t)12912640)   // f32 [2] : cq + b_score, ck

// =====================================================================
// Kernel CAST: ops (f32) -> ops16 (bf16), 8 elems/thread.
// =====================================================================
__global__ __launch_bounds__(256) void k_cast(
    const float* __restrict__ src, bf16* __restrict__ dst)
{
    int i = blockIdx.x * 256 + threadIdx.x;
    f32x4 a = *(const f32x4*)(src + (size_t)i * 8);
    f32x4 b = *(const f32x4*)(src + (size_t)i * 8 + 4);
    bf16x8 o;
    #pragma unroll
    for (int e = 0; e < 4; ++e) { o[e] = (bf16)a[e]; o[4 + e] = (bf16)b[e]; }
    *(bf16x8*)(dst + (size_t)i * 8) = o;
}

// =====================================================================
// Kernel P: fold weights (all inputs f32; folded outputs bf16/f32).
//   GtT[e][d] = sum_f L[d][f] * R[f][e]  (stored transposed, bf16)
//   uq[d] = sum_e Wqkv[d][e]*ws[e], uk[d] = sum_e Wqkv[d][128+e]*ws[128+e]
//   BBM[e] = b_mix3@Wm2a + b_out@Wm2b + b_mix2 ; BBB/BBE likewise
//   sc = {b_qkv[:D].ws_q + b_score, b_qkv[D:2D].ws_k}
// =====================================================================
__global__ __launch_bounds__(256) void k_prep(
    const float* __restrict__ Wmix3, const float* __restrict__ Wmix2,
    const float* __restrict__ Wout,  const float* __restrict__ Wbegin,
    const float* __restrict__ Wend,  const float* __restrict__ Wqkv,
    const float* __restrict__ bqkv,  const float* __restrict__ wscore,
    const float* __restrict__ bscore,const float* __restrict__ bmix3,
    const float* __restrict__ bout,  const float* __restrict__ bmix2,
    const float* __restrict__ bbegin,const float* __restrict__ bend,
    bf16* __restrict__ G1T, bf16* __restrict__ G2T, bf16* __restrict__ G3T,
    bf16* __restrict__ WCT, bf16* __restrict__ GBT, bf16* __restrict__ GET,
    bf16* __restrict__ uqk, float* __restrict__ BBM, float* __restrict__ BBB,
    float* __restrict__ BBE, float* __restrict__ sc)
{
    int wg = blockIdx.x;
    int t = threadIdx.x;
    if (wg < 96) {
        int mat = wg >> 4, sub = wg & 15;
        const float* L; const float* R; bf16* O;
        switch (mat) {
            case 0: L = Wmix3;           R = Wmix2;           O = G1T; break;
            case 1: L = Wmix3 + 128*128; R = Wmix2;           O = G2T; break;
            case 2: L = Wmix3 + 256*128; R = Wmix2;           O = G3T; break;
            case 3: L = Wout;            R = Wmix2 + 128*128; O = WCT; break;
            case 4: L = Wbegin;          R = Wmix2;           O = GBT; break;
            default:L = Wend;            R = Wmix2;           O = GET; break;
        }
        int e  = sub * 8 + (t >> 5);
        int d0 = (t & 31) * 4;
        float s[4] = {0.f, 0.f, 0.f, 0.f};
        for (int f = 0; f < 128; ++f) {
            float rv = R[f*128 + e];
            #pragma unroll
            for (int dd = 0; dd < 4; ++dd)
                s[dd] += L[(d0+dd)*128 + f] * rv;
        }
        #pragma unroll
        for (int dd = 0; dd < 4; ++dd)
            O[e*128 + d0 + dd] = (bf16)s[dd];
    } else {
        if (t < 128) {
            int d = t;
            float su = 0.f, sk_ = 0.f;
            for (int e2 = 0; e2 < 128; ++e2) {
                su  += Wqkv[d*384 + e2]       * wscore[e2];
                sk_ += Wqkv[d*384 + 128 + e2] * wscore[128 + e2];
            }
            uqk[d]       = (bf16)su;
            uqk[128 + d] = (bf16)sk_;
            int e = d;
            float bm = 0.f, bon = 0.f, bb_ = 0.f, be_ = 0.f;
            for (int f = 0; f < 128; ++f) {
                float w2a = Wmix2[f*128 + e];
                float w2b = Wmix2[(128+f)*128 + e];
                bm  += bmix3[f]  * w2a;
                bon += bout[f]   * w2b;
                bb_ += bbegin[f] * w2a;
                be_ += bend[f]   * w2a;
            }
            float bm2 = bmix2[e];
            BBM[e] = bm  + bon + bm2;
            BBB[e] = bb_ + bon + bm2;
            BBE[e] = be_ + bon + bm2;
        } else if (t == 128) {
            float cq = 0.f, ck = 0.f;
            for (int e2 = 0; e2 < 128; ++e2) {
                cq += bqkv[e2]       * wscore[e2];
                ck += bqkv[128 + e2] * wscore[128 + e2];
            }
            sc[0] = cq + bscore[0];
            sc[1] = ck;
        }
    }
}

// =====================================================================
// Kernel V: VT[b][n][j] = (ops@Wv + b_v)^T  via MFMA with A=Wv^T (LDS),
// B=ops16 rows (global, d-contiguous). Extra A-rows 128/129 = uq/uk give
// sq/sk for free. Grid: 8*16 wgs, 256 thr; wave w owns j-block of 32.
// =====================================================================
__global__ __launch_bounds__(256) void k_v(
    const bf16* __restrict__ ops16, const float* __restrict__ Wqkv,
    const float* __restrict__ bqkv, const bf16* __restrict__ uqk,
    const float* __restrict__ sc,
    bf16* __restrict__ VT, float* __restrict__ sqf, float* __restrict__ skf)
{
    __shared__ bf16 A[144 * 136];
    int b  = blockIdx.x >> 4;
    int jt = (blockIdx.x & 15) * 128;
    int t  = threadIdx.x;
    // stage Wv^T : A[n][d] = Wqkv[d][256+n]  (convert f32 -> bf16)
    {
        int d = t >> 1, half = t & 1;
        const float* src = Wqkv + d*384 + 256 + half*64;
        #pragma unroll
        for (int e = 0; e < 64; ++e)
            A[(half*64 + e)*136 + d] = (bf16)src[e];
    }
    { // rows 128,129 = uq,uk
        int row = t >> 7, col = t & 127;
        A[(128 + row)*136 + col] = uqk[row*128 + col];
    }
    for (int idx = t; idx < 14*136; idx += 256)   // zero pad rows 130..143
        A[130*136 + idx] = (bf16)0.f;
    __syncthreads();

    int lane = t & 63, w = t >> 6;
    int m = lane & 15, q = lane >> 4;
    f32x4 acc[9][2];
    #pragma unroll
    for (int rb = 0; rb < 9; ++rb)
        #pragma unroll
        for (int cb = 0; cb < 2; ++cb)
            acc[rb][cb] = {0.f, 0.f, 0.f, 0.f};

    const bf16* opsb = ops16 + (size_t)b * CC * DD;
    #pragma unroll
    for (int kc = 0; kc < 4; ++kc) {
        bf16x8 bfr[2];
        #pragma unroll
        for (int cb = 0; cb < 2; ++cb) {
            int j = jt + w*32 + cb*16 + m;
            bfr[cb] = *(const bf16x8*)(opsb + (size_t)j*DD + kc*32 + q*8);
        }
        #pragma unroll
        for (int rb = 0; rb < 9; ++rb) {
            bf16x8 afr = *(const bf16x8*)&A[(rb*16 + m)*136 + kc*32 + q*8];
            acc[rb][0] = MFMA16(afr, bfr[0], acc[rb][0]);
            acc[rb][1] = MFMA16(afr, bfr[1], acc[rb][1]);
        }
    }
    float cqb = sc[0], ckv = sc[1];
    #pragma unroll
    for (int cb = 0; cb < 2; ++cb) {
        int j = jt + w*32 + cb*16 + m;
        #pragma unroll
        for (int rb = 0; rb < 8; ++rb) {
            #pragma unroll
            for (int r = 0; r < 4; ++r) {
                int n = rb*16 + q*4 + r;
                float v = acc[rb][cb][r] + bqkv[256 + n];
                VT[((size_t)b*DD + n)*CC + j] = (bf16)v;
            }
        }
        if (q == 0) {
            sqf[b*CC + j] = acc[8][cb][0] + cqb;   // row 128 = uq
            skf[b*CC + j] = acc[8][cb][1] + ckv;   // row 129 = uk
        }
    }
}

// =====================================================================
// Kernel ATT: unnormalized streaming softmax-GEMM.
// One wave per 16-row i-tile; P built directly in A-fragment layout;
// 2-deep software pipeline over j-chunks of 32. Mask is f32, streamed
// nontemporal (single use, 134 MB).
// =====================================================================
struct AttBuf { f32x4 mk0, mk1, s0, s1; bf16x8 vb[8]; };

__device__ __forceinline__ void att_load(int jc, int q, int m,
    const float* __restrict__ maskrow, const float* __restrict__ skrow,
    const bf16* __restrict__ vtb, AttBuf& Bu)
{
    int jj = jc*32 + q*8;
    Bu.mk0 = __builtin_nontemporal_load((const f32x4*)(maskrow + jj));
    Bu.mk1 = __builtin_nontemporal_load((const f32x4*)(maskrow + jj + 4));
    Bu.s0 = *(const f32x4*)(skrow + jj);
    Bu.s1 = *(const f32x4*)(skrow + jj + 4);
    #pragma unroll
    for (int nb = 0; nb < 8; ++nb)
        Bu.vb[nb] = *(const bf16x8*)(vtb + ((size_t)(nb*16 + m))*CC + jj);
}

__device__ __forceinline__ void att_step(const AttBuf& Bu, float sq,
                                         float& lsum, f32x4 acc[8])
{
    float sks[8] = {Bu.s0[0], Bu.s0[1], Bu.s0[2], Bu.s0[3],
                    Bu.s1[0], Bu.s1[1], Bu.s1[2], Bu.s1[3]};
    float mks[8] = {Bu.mk0[0], Bu.mk0[1], Bu.mk0[2], Bu.mk0[3],
                    Bu.mk1[0], Bu.mk1[1], Bu.mk1[2], Bu.mk1[3]};
    bf16x8 a;
    #pragma unroll
    for (int e = 0; e < 8; ++e) {
        float tv = sq + sks[e];
        float lr = fmaxf(tv, 0.01f * tv);      // leaky_relu, slope 0.01
        float z  = lr * mks[e];                // multiplicative mask
        float p  = __expf(z);                  // no max-shift needed: |z| < 1
        lsum += p;
        a[e] = (bf16)p;
    }
    #pragma unroll
    for (int nb = 0; nb < 8; ++nb)
        acc[nb] = MFMA16(a, Bu.vb[nb], acc[nb]);
}

__global__ __launch_bounds__(256) void k_att(
    const float* __restrict__ mask, const bf16* __restrict__ VT,
    const float* __restrict__ sqf, const float* __restrict__ skf,
    bf16* __restrict__ Oatt)
{
    int lane = threadIdx.x & 63;
    int w    = threadIdx.x >> 6;
    int tile = blockIdx.x * 4 + w;      // 1024 tiles
    int b    = tile >> 7;
    int i0   = (tile & 127) << 4;
    int m = lane & 15, q = lane >> 4;
    int i = i0 + m;

    float sq = sqf[b*CC + i];
    f32x4 acc[8];
    #pragma unroll
    for (int nb = 0; nb < 8; ++nb) acc[nb] = {0.f, 0.f, 0.f, 0.f};
    float lsum = 0.f;

    const float* maskrow = mask + ((size_t)(b*CC + i)) * CC;
    const float* skrow   = skf + b*CC;
    const bf16*  vtb     = VT + (size_t)b * DD * CC;

    AttBuf bufA, bufB;
    att_load(0, q, m, maskrow, skrow, vtb, bufA);
    for (int jc = 0; jc < 64; jc += 2) {
        att_load(jc + 1, q, m, maskrow, skrow, vtb, bufB);
        att_step(bufA, sq, lsum, acc);
        if (jc + 2 < 64) att_load(jc + 2, q, m, maskrow, skrow, vtb, bufA);
        att_step(bufB, sq, lsum, acc);
    }

    // row-sum of exp: partials live on the 4 quads of each row m
    lsum += __shfl_xor(lsum, 16, 64);
    lsum += __shfl_xor(lsum, 32, 64);
    float inv[4];
    #pragma unroll
    for (int r = 0; r < 4; ++r) {
        float lr_ = __shfl(lsum, q*4 + r, 64);  // lane (q*4+r) holds row q*4+r
        inv[r] = 1.0f / lr_;
    }
    bf16* ob = Oatt + ((size_t)b*CC + i0) * DD;
    #pragma unroll
    for (int nb = 0; nb < 8; ++nb)
        #pragma unroll
        for (int r = 0; r < 4; ++r)
            ob[(size_t)(q*4 + r)*DD + nb*16 + m] = (bf16)(acc[nb][r] * inv[r]);
}

// =====================================================================
// Kernel EPI: out[c] = ops[c]@G1 + ops[pred]@G2 + ops[succ]@G3
//                    + O_att[c]@Wc + BBM,  rows c < 2046 of each batch.
// 128 wgs (b, 128-row tile); 4 accumulation terms through shared LDS.
// Output f32.
// =====================================================================
__global__ __launch_bounds__(256) void k_epi(
    const bf16* __restrict__ ops16, const int* __restrict__ relations,
    const bf16* __restrict__ Oatt,
    const bf16* __restrict__ G1T, const bf16* __restrict__ G2T,
    const bf16* __restrict__ G3T, const bf16* __restrict__ WCT,
    const float* __restrict__ BBM, float* __restrict__ out)
{
    __shared__ bf16 Abuf[128 * 136];
    __shared__ bf16 Bbuf[128 * 136];
    int b  = blockIdx.x >> 4;
    int c0 = (blockIdx.x & 15) * 128;
    int t  = threadIdx.x;
    int lane = t & 63, w = t >> 6;
    int m = lane & 15, q = lane >> 4;

    f32x4 acc[8][2];
    #pragma unroll
    for (int rb = 0; rb < 8; ++rb)
        #pragma unroll
        for (int cb = 0; cb < 2; ++cb)
            acc[rb][cb] = {0.f, 0.f, 0.f, 0.f};

    const bf16* Bsrc[4] = {G1T, G2T, G3T, WCT};
    int row = t >> 1, half = t & 1;
    int c = c0 + row;

    for (int term = 0; term < 4; ++term) {
        const bf16* src;
        if (term == 0)      src = ops16 + ((size_t)(b*CC + c)) * DD;
        else if (term == 3) src = Oatt  + ((size_t)(b*CC + c)) * DD;
        else {
            int cc = min(c, CC - 3);
            int ridx = relations[((size_t)b*(CC-2) + cc)*2 + (term - 1)];
            src = ops16 + ((size_t)(b*CC) + ridx) * DD;
        }
        const uint4* s4 = (const uint4*)(src + half*64);
        uint4* d4 = (uint4*)&Abuf[row*136 + half*64];
        #pragma unroll
        for (int ii = 0; ii < 8; ++ii) d4[ii] = s4[ii];

        const uint4* bs = (const uint4*)(Bsrc[term] + row*128 + half*64);
        uint4* bd = (uint4*)&Bbuf[row*136 + half*64];
        #pragma unroll
        for (int ii = 0; ii < 8; ++ii) bd[ii] = bs[ii];
        __syncthreads();

        #pragma unroll
        for (int kc = 0; kc < 4; ++kc) {
            bf16x8 bfr[2];
            #pragma unroll
            for (int cb = 0; cb < 2; ++cb)
                bfr[cb] = *(const bf16x8*)&Bbuf[(w*32 + cb*16 + m)*136 + kc*32 + q*8];
            #pragma unroll
            for (int rb = 0; rb < 8; ++rb) {
                bf16x8 afr = *(const bf16x8*)&Abuf[(rb*16 + m)*136 + kc*32 + q*8];
                acc[rb][0] = MFMA16(afr, bfr[0], acc[rb][0]);
                acc[rb][1] = MFMA16(afr, bfr[1], acc[rb][1]);
            }
        }
        __syncthreads();
    }
    #pragma unroll
    for (int cb = 0; cb < 2; ++cb) {
        int col = w*32 + cb*16 + m;
        float bias = BBM[col];
        #pragma unroll
        for (int rb = 0; rb < 8; ++rb) {
            #pragma unroll
            for (int r = 0; r < 4; ++r) {
                int cg = c0 + rb*16 + q*4 + r;
                if (cg < CC - 2)
                    out[((size_t)(b*CC) + cg)*DD + col] = acc[rb][cb][r] + bias;
            }
        }
    }
}

// =====================================================================
// Kernel EDGE: rows 2046 (begin) / 2047 (end). Output f32.
//   out = mean(gather(ops,idx)) @ (W_{b/e}@Wm2a) + O_att[row]@Wc + BB{B/E}
// =====================================================================
__global__ __launch_bounds__(128) void k_edge(
    const bf16* __restrict__ ops16, const int* __restrict__ begins,
    const int* __restrict__ ends, const bf16* __restrict__ Oatt,
    const bf16* __restrict__ GBT, const bf16* __restrict__ GET,
    const bf16* __restrict__ WCT, const float* __restrict__ BBB,
    const float* __restrict__ BBE, float* __restrict__ out)
{
    __shared__ float meanv[128];
    int b = blockIdx.x >> 1, which = blockIdx.x & 1;
    int t = threadIdx.x;
    const int* idx = which ? (ends + b*JJN) : (begins + b*JJN);
    const bf16* opsb = ops16 + (size_t)b * CC * DD;
    float s = 0.f;
    for (int j = 0; j < JJN; ++j) {
        int r = idx[j];
        s += (float)opsb[(size_t)r*DD + t];
    }
    meanv[t] = s * (1.0f / (float)JJN);
    __syncthreads();
    const bf16* G  = which ? GET : GBT;
    const float* Bv = which ? BBE : BBB;
    const bf16* orow = Oatt + ((size_t)b*CC + (CC - 2 + which)) * DD;
    float a = Bv[t];
    const bf16* gr = G + t*128;
    const bf16* wr = WCT + t*128;
    for (int d = 0; d < 128; ++d) {
        a += meanv[d] * (float)gr[d];
        a += (float)orow[d] * (float)wr[d];
    }
    out[((size_t)b*CC + (CC - 2 + which))*DD + t] = a;
}

// =====================================================================
extern "C" void kernel_launch(void* const* d_in, const int* in_sizes, int n_in,
                              void* d_out, int out_size, void* d_ws, size_t ws_size,
                              hipStream_t stream)
{
    const float* ops      = (const float*)d_in[0];
    const int*  relations = (const int*)d_in[1];
    const int*  begins    = (const int*)d_in[2];
    const int*  ends      = (const int*)d_in[3];
    const float* mask     = (const float*)d_in[4];
    const float* Wbegin   = (const float*)d_in[5];
    const float* bbegin   = (const float*)d_in[6];
    const float* Wend     = (const float*)d_in[7];
    const float* bend     = (const float*)d_in[8];
    const float* Wmix3    = (const float*)d_in[9];
    const float* bmix3    = (const float*)d_in[10];
    const float* Wqkv     = (const float*)d_in[11];
    const float* bqkv     = (const float*)d_in[12];
    const float* wscore   = (const float*)d_in[13];
    const float* bscore   = (const float*)d_in[14];
    const float* Wout     = (const float*)d_in[15];
    const float* bout     = (const float*)d_in[16];
    const float* Wmix2    = (const float*)d_in[17];
    const float* bmix2    = (const float*)d_in[18];
    float* outp = (float*)d_out;

    char* ws = (char*)d_ws;
    bf16*  VT    = (bf16*)(ws + WS_VT);
    bf16*  Oatt  = (bf16*)(ws + WS_OATT);
    bf16*  OPS16 = (bf16*)(ws + WS_OPS16);
    float* sqf   = (float*)(ws + WS_SQF);
    float* skf   = (float*)(ws + WS_SKF);
    bf16*  G1T   = (bf16*)(ws + WS_G1T);
    bf16*  G2T   = (bf16*)(ws + WS_G2T);
    bf16*  G3T   = (bf16*)(ws + WS_G3T);
    bf16*  WCT   = (bf16*)(ws + WS_WCT);
    bf16*  GBT   = (bf16*)(ws + WS_GBT);
    bf16*  GET   = (bf16*)(ws + WS_GET);
    bf16*  UQK   = (bf16*)(ws + WS_UQK);
    float* BBM   = (float*)(ws + WS_BBM);
    float* BBB   = (float*)(ws + WS_BBB);
    float* BBE   = (float*)(ws + WS_BBE);
    float* SC    = (float*)(ws + WS_SC);

    k_prep<<<dim3(97), dim3(256), 0, stream>>>(
        Wmix3, Wmix2, Wout, Wbegin, Wend, Wqkv, bqkv, wscore, bscore,
        bmix3, bout, bmix2, bbegin, bend,
        G1T, G2T, G3T, WCT, GBT, GET, UQK, BBM, BBB, BBE, SC);

    // 8*2048*128 / 8 elems per thread / 256 threads = 1024 blocks
    k_cast<<<dim3(1024), dim3(256), 0, stream>>>(ops, OPS16);

    k_v<<<dim3(128), dim3(256), 0, stream>>>(
        OPS16, Wqkv, bqkv, UQK, SC, VT, sqf, skf);

    k_att<<<dim3(256), dim3(256), 0, stream>>>(
        mask, VT, sqf, skf, Oatt);

    k_epi<<<dim3(128), dim3(256), 0, stream>>>(
        OPS16, relations, Oatt, G1T, G2T, G3T, WCT, BBM, outp);

    k_edge<<<dim3(16), dim3(128), 0, stream>>>(
        OPS16, begins, ends, Oatt, GBT, GET, WCT, BBB, BBE, outp);
}

// Round 3
// 339.778 us; speedup vs baseline: 1.0301x; 1.0301x over previous
//
#include <hip/hip_runtime.h>
#include <cstddef>

typedef __bf16 bf16;
typedef __bf16 bf16x4 __attribute__((ext_vector_type(4)));
typedef __bf16 bf16x8 __attribute__((ext_vector_type(8)));
typedef float  f32x4  __attribute__((ext_vector_type(4)));

#define MFMA16(a, b, c) __builtin_amdgcn_mfma_f32_16x16x32_bf16((a), (b), (c), 0, 0, 0)

// ---------------- constants ----------------
#define BB 8
#define CC 2048
#define DD 128
#define JJN 128

// ws layout (bytes)
#define WS_VT    ((size_t)0)          // bf16 [8][128][2048]  (V transposed)
#define WS_OATT  ((size_t)4194304)    // bf16 [8][2048][128]
#define WS_OPS16 ((size_t)8388608)    // bf16 [8][2048][128]  (ops cast to bf16)
#define WS_SQF   ((size_t)12582912)   // f32  [8][2048]
#define WS_SKF   ((size_t)12648448)   // f32  [8][2048]
#define WS_G1T   ((size_t)12713984)   // bf16 [128][128] (transposed: [e][d])
#define WS_G2T   ((size_t)12746752)
#define WS_G3T   ((size_t)12779520)
#define WS_WCT   ((size_t)12812288)
#define WS_GBT   ((size_t)12845056)
#define WS_GET   ((size_t)12877824)
#define WS_UQK   ((size_t)12910592)   // bf16 [2][128]  (uq row, uk row)
#define WS_BBM   ((size_t)12911104)   // f32 [128]
#define WS_BBB   ((size_t)12911616)   // f32 [128]
#define WS_BBE   ((size_t)12912128)   // f32 [128]
#define WS_SC    ((size_t)12912640)   // f32 [2] : cq + b_score, ck

// =====================================================================
// Kernel PREPCAST: blocks 0..1023 cast ops f32->bf16; blocks 1024..1119
// fold weight products via LDS-staged coalesced loads; block 1120 does
// the small vector folds.
// =====================================================================
__global__ __launch_bounds__(256) void k_prepcast(
    const float* __restrict__ ops, bf16* __restrict__ ops16,
    const float* __restrict__ Wmix3, const float* __restrict__ Wmix2,
    const float* __restrict__ Wout,  const float* __restrict__ Wbegin,
    const float* __restrict__ Wend,  const float* __restrict__ Wqkv,
    const float* __restrict__ bqkv,  const float* __restrict__ wscore,
    const float* __restrict__ bscore,const float* __restrict__ bmix3,
    const float* __restrict__ bout,  const float* __restrict__ bmix2,
    const float* __restrict__ bbegin,const float* __restrict__ bend,
    bf16* __restrict__ G1T, bf16* __restrict__ G2T, bf16* __restrict__ G3T,
    bf16* __restrict__ WCT, bf16* __restrict__ GBT, bf16* __restrict__ GET,
    bf16* __restrict__ uqk, float* __restrict__ BBM, float* __restrict__ BBB,
    float* __restrict__ BBE, float* __restrict__ sc)
{
    __shared__ bf16  LshT[128 * 132];   // L transposed: [f][d], bf16
    __shared__ float Rsh[128 * 8];      // R columns e0..e0+7: [f][ee]
    int wg = blockIdx.x;
    int t  = threadIdx.x;

    if (wg < 1024) {
        // ---- cast ----
        size_t i = (size_t)wg * 256 + t;
        f32x4 a = *(const f32x4*)(ops + i * 8);
        f32x4 b = *(const f32x4*)(ops + i * 8 + 4);
        bf16x8 o;
        #pragma unroll
        for (int e = 0; e < 4; ++e) { o[e] = (bf16)a[e]; o[4 + e] = (bf16)b[e]; }
        *(bf16x8*)(ops16 + i * 8) = o;
        return;
    }
    if (wg < 1120) {
        // ---- matmul fold: GtT[e][d] = sum_f L[d][f]*R[f][e] ----
        int id  = wg - 1024;
        int mat = id >> 4, sub = id & 15;
        const float* L; const float* R; bf16* O;
        switch (mat) {
            case 0: L = Wmix3;           R = Wmix2;           O = G1T; break;
            case 1: L = Wmix3 + 128*128; R = Wmix2;           O = G2T; break;
            case 2: L = Wmix3 + 256*128; R = Wmix2;           O = G3T; break;
            case 3: L = Wout;            R = Wmix2 + 128*128; O = WCT; break;
            case 4: L = Wbegin;          R = Wmix2;           O = GBT; break;
            default:L = Wend;            R = Wmix2;           O = GET; break;
        }
        int e0 = sub * 8;
        // stage L (row-major [d][f]) transposed into LshT[f][d], bf16
        #pragma unroll
        for (int pass = 0; pass < 16; ++pass) {
            int idx = pass * 256 + t;          // over 4096 float4's
            int d   = idx >> 5;                // 0..127
            int f0  = (idx & 31) * 4;          // 0..124
            f32x4 v = *(const f32x4*)(L + d * 128 + f0);
            #pragma unroll
            for (int jj = 0; jj < 4; ++jj)
                LshT[(f0 + jj) * 132 + d] = (bf16)v[jj];
        }
        // stage R columns e0..e0+7: Rsh[f][ee]
        #pragma unroll
        for (int pass = 0; pass < 4; ++pass) {
            int idx = pass * 256 + t;          // over 1024 elems
            int f   = idx >> 3;
            int ee  = idx & 7;
            Rsh[f * 8 + ee] = R[f * 128 + e0 + ee];
        }
        __syncthreads();
        int ee = t >> 5;            // 0..7
        int e  = e0 + ee;
        int d0 = (t & 31) * 4;
        float s[4] = {0.f, 0.f, 0.f, 0.f};
        for (int f = 0; f < 128; ++f) {
            bf16x4 lv = *(const bf16x4*)&LshT[f * 132 + d0];
            float rv = Rsh[f * 8 + ee];
            #pragma unroll
            for (int dd = 0; dd < 4; ++dd)
                s[dd] += (float)lv[dd] * rv;
        }
        #pragma unroll
        for (int dd = 0; dd < 4; ++dd)
            O[e * 128 + d0 + dd] = (bf16)s[dd];
        return;
    }
    // ---- vector folds (block 1120) ----
    if (t < 128) {
        int d = t;
        float su = 0.f, sk_ = 0.f;
        for (int e2 = 0; e2 < 128; ++e2) {
            su  += Wqkv[d*384 + e2]       * wscore[e2];
            sk_ += Wqkv[d*384 + 128 + e2] * wscore[128 + e2];
        }
        uqk[d]       = (bf16)su;
        uqk[128 + d] = (bf16)sk_;
        int e = d;
        float bm = 0.f, bon = 0.f, bb_ = 0.f, be_ = 0.f;
        for (int f = 0; f < 128; ++f) {
            float w2a = Wmix2[f*128 + e];
            float w2b = Wmix2[(128+f)*128 + e];
            bm  += bmix3[f]  * w2a;
            bon += bout[f]   * w2b;
            bb_ += bbegin[f] * w2a;
            be_ += bend[f]   * w2a;
        }
        float bm2 = bmix2[e];
        BBM[e] = bm  + bon + bm2;
        BBB[e] = bb_ + bon + bm2;
        BBE[e] = be_ + bon + bm2;
    } else if (t == 128) {
        float cq = 0.f, ck = 0.f;
        for (int e2 = 0; e2 < 128; ++e2) {
            cq += bqkv[e2]       * wscore[e2];
            ck += bqkv[128 + e2] * wscore[128 + e2];
        }
        sc[0] = cq + bscore[0];
        sc[1] = ck;
    }
}

// =====================================================================
// Kernel V: VT[b][n][j] = (ops@Wv + b_v)^T  via MFMA with A=Wv^T (LDS),
// B=ops16 rows (global, d-contiguous). Extra A-rows 128/129 = uq/uk give
// sq/sk for free. Grid: 8*16 wgs, 256 thr; wave w owns j-block of 32.
// =====================================================================
__global__ __launch_bounds__(256) void k_v(
    const bf16* __restrict__ ops16, const float* __restrict__ Wqkv,
    const float* __restrict__ bqkv, const bf16* __restrict__ uqk,
    const float* __restrict__ sc,
    bf16* __restrict__ VT, float* __restrict__ sqf, float* __restrict__ skf)
{
    __shared__ bf16 A[144 * 136];
    int b  = blockIdx.x >> 4;
    int jt = (blockIdx.x & 15) * 128;
    int t  = threadIdx.x;
    // stage Wv^T : A[n][d] = Wqkv[d][256+n]  (coalesced float4 in n)
    #pragma unroll
    for (int pass = 0; pass < 16; ++pass) {
        int idx = pass * 256 + t;
        int d   = idx >> 5;
        int n0  = (idx & 31) * 4;
        f32x4 v = *(const f32x4*)(Wqkv + d*384 + 256 + n0);
        #pragma unroll
        for (int jj = 0; jj < 4; ++jj)
            A[(n0 + jj)*136 + d] = (bf16)v[jj];
    }
    { // rows 128,129 = uq,uk
        int row = t >> 7, col = t & 127;
        A[(128 + row)*136 + col] = uqk[row*128 + col];
    }
    for (int idx = t; idx < 14*136; idx += 256)   // zero pad rows 130..143
        A[130*136 + idx] = (bf16)0.f;
    __syncthreads();

    int lane = t & 63, w = t >> 6;
    int m = lane & 15, q = lane >> 4;
    f32x4 acc[9][2];
    #pragma unroll
    for (int rb = 0; rb < 9; ++rb)
        #pragma unroll
        for (int cb = 0; cb < 2; ++cb)
            acc[rb][cb] = {0.f, 0.f, 0.f, 0.f};

    const bf16* opsb = ops16 + (size_t)b * CC * DD;
    #pragma unroll
    for (int kc = 0; kc < 4; ++kc) {
        bf16x8 bfr[2];
        #pragma unroll
        for (int cb = 0; cb < 2; ++cb) {
            int j = jt + w*32 + cb*16 + m;
            bfr[cb] = *(const bf16x8*)(opsb + (size_t)j*DD + kc*32 + q*8);
        }
        #pragma unroll
        for (int rb = 0; rb < 9; ++rb) {
            bf16x8 afr = *(const bf16x8*)&A[(rb*16 + m)*136 + kc*32 + q*8];
            acc[rb][0] = MFMA16(afr, bfr[0], acc[rb][0]);
            acc[rb][1] = MFMA16(afr, bfr[1], acc[rb][1]);
        }
    }
    float cqb = sc[0], ckv = sc[1];
    #pragma unroll
    for (int cb = 0; cb < 2; ++cb) {
        int j = jt + w*32 + cb*16 + m;
        #pragma unroll
        for (int rb = 0; rb < 8; ++rb) {
            #pragma unroll
            for (int r = 0; r < 4; ++r) {
                int n = rb*16 + q*4 + r;
                float v = acc[rb][cb][r] + bqkv[256 + n];
                VT[((size_t)b*DD + n)*CC + j] = (bf16)v;
            }
        }
        if (q == 0) {
            sqf[b*CC + j] = acc[8][cb][0] + cqb;   // row 128 = uq
            skf[b*CC + j] = acc[8][cb][1] + ckv;   // row 129 = uk
        }
    }
}

// =====================================================================
// Kernel ATT: unnormalized streaming softmax-GEMM, j split 4-way.
// One BLOCK per 16-row i-tile (1024 blocks); wave w handles j-quarter
// [w*512, w*512+512); partials combined through LDS; normalized write.
// =====================================================================
struct AttBuf { f32x4 mk0, mk1, s0, s1; bf16x8 vb[8]; };

__device__ __forceinline__ void att_load(int jc, int q, int m,
    const float* __restrict__ maskrow, const float* __restrict__ skrow,
    const bf16* __restrict__ vtb, AttBuf& Bu)
{
    int jj = jc*32 + q*8;
    Bu.mk0 = __builtin_nontemporal_load((const f32x4*)(maskrow + jj));
    Bu.mk1 = __builtin_nontemporal_load((const f32x4*)(maskrow + jj + 4));
    Bu.s0 = *(const f32x4*)(skrow + jj);
    Bu.s1 = *(const f32x4*)(skrow + jj + 4);
    #pragma unroll
    for (int nb = 0; nb < 8; ++nb)
        Bu.vb[nb] = *(const bf16x8*)(vtb + ((size_t)(nb*16 + m))*CC + jj);
}

__device__ __forceinline__ void att_step(const AttBuf& Bu, float sq,
                                         float& lsum, f32x4 acc[8])
{
    float sks[8] = {Bu.s0[0], Bu.s0[1], Bu.s0[2], Bu.s0[3],
                    Bu.s1[0], Bu.s1[1], Bu.s1[2], Bu.s1[3]};
    float mks[8] = {Bu.mk0[0], Bu.mk0[1], Bu.mk0[2], Bu.mk0[3],
                    Bu.mk1[0], Bu.mk1[1], Bu.mk1[2], Bu.mk1[3]};
    bf16x8 a;
    #pragma unroll
    for (int e = 0; e < 8; ++e) {
        float tv = sq + sks[e];
        float lr = fmaxf(tv, 0.01f * tv);      // leaky_relu, slope 0.01
        float z  = lr * mks[e];                // multiplicative mask
        float p  = __expf(z);                  // no max-shift needed: |z| < 1
        lsum += p;
        a[e] = (bf16)p;
    }
    #pragma unroll
    for (int nb = 0; nb < 8; ++nb)
        acc[nb] = MFMA16(a, Bu.vb[nb], acc[nb]);
}

__global__ __launch_bounds__(256) void k_att(
    const float* __restrict__ mask, const bf16* __restrict__ VT,
    const float* __restrict__ sqf, const float* __restrict__ skf,
    bf16* __restrict__ Oatt)
{
    __shared__ float Osh[4 * 16 * 132];   // [wave][row][col(pad)]
    __shared__ float Lsh[4 * 16];
    int t    = threadIdx.x;
    int lane = t & 63;
    int w    = t >> 6;                  // j-quarter
    int tile = blockIdx.x;              // 1024 tiles
    int b    = tile >> 7;
    int i0   = (tile & 127) << 4;
    int m = lane & 15, q = lane >> 4;
    int i = i0 + m;

    float sq = sqf[b*CC + i];
    f32x4 acc[8];
    #pragma unroll
    for (int nb = 0; nb < 8; ++nb) acc[nb] = {0.f, 0.f, 0.f, 0.f};
    float lsum = 0.f;

    const float* maskrow = mask + ((size_t)(b*CC + i)) * CC;
    const float* skrow   = skf + b*CC;
    const bf16*  vtb     = VT + (size_t)b * DD * CC;

    int jc0 = w * 16;                  // 16 chunks of 32 j per wave
    AttBuf bufA, bufB;
    att_load(jc0, q, m, maskrow, skrow, vtb, bufA);
    for (int s = 0; s < 16; s += 2) {
        att_load(jc0 + s + 1, q, m, maskrow, skrow, vtb, bufB);
        att_step(bufA, sq, lsum, acc);
        if (s + 2 < 16) att_load(jc0 + s + 2, q, m, maskrow, skrow, vtb, bufA);
        att_step(bufB, sq, lsum, acc);
    }

    // full row-sum for this wave's j-quarter
    lsum += __shfl_xor(lsum, 16, 64);
    lsum += __shfl_xor(lsum, 32, 64);
    if (q == 0) Lsh[w*16 + m] = lsum;
    // stash partial O
    #pragma unroll
    for (int nb = 0; nb < 8; ++nb)
        #pragma unroll
        for (int r = 0; r < 4; ++r)
            Osh[(w*16 + q*4 + r)*132 + nb*16 + m] = acc[nb][r];
    __syncthreads();

    // combine + normalize + write: thread -> (row r, 8-col chunk)
    int r  = t >> 4;
    int c0 = (t & 15) * 8;
    float l = Lsh[r] + Lsh[16 + r] + Lsh[32 + r] + Lsh[48 + r];
    float inv = 1.0f / l;
    bf16x8 o;
    #pragma unroll
    for (int e = 0; e < 8; ++e) {
        float s = Osh[(r)*132 + c0 + e] + Osh[(16 + r)*132 + c0 + e]
                + Osh[(32 + r)*132 + c0 + e] + Osh[(48 + r)*132 + c0 + e];
        o[e] = (bf16)(s * inv);
    }
    *(bf16x8*)(Oatt + ((size_t)(b*CC) + i0 + r)*DD + c0) = o;
}

// =====================================================================
// Kernel EPI: out[c] = ops[c]@G1 + ops[pred]@G2 + ops[succ]@G3
//                    + O_att[c]@Wc + BBM,  rows c < 2046 of each batch.
// 256 wgs (b, 64-row tile); 4 accumulation terms through shared LDS.
// Output f32.
// =====================================================================
__global__ __launch_bounds__(256) void k_epi(
    const bf16* __restrict__ ops16, const int* __restrict__ relations,
    const bf16* __restrict__ Oatt,
    const bf16* __restrict__ G1T, const bf16* __restrict__ G2T,
    const bf16* __restrict__ G3T, const bf16* __restrict__ WCT,
    const float* __restrict__ BBM, float* __restrict__ out)
{
    __shared__ bf16 Abuf[64 * 136];
    __shared__ bf16 Bbuf[128 * 136];
    int b  = blockIdx.x >> 5;
    int c0 = (blockIdx.x & 31) * 64;
    int t  = threadIdx.x;
    int lane = t & 63, w = t >> 6;
    int m = lane & 15, q = lane >> 4;

    f32x4 acc[4][2];
    #pragma unroll
    for (int rb = 0; rb < 4; ++rb)
        #pragma unroll
        for (int cb = 0; cb < 2; ++cb)
            acc[rb][cb] = {0.f, 0.f, 0.f, 0.f};

    const bf16* Bsrc[4] = {G1T, G2T, G3T, WCT};
    int arow = t >> 2, aq = t & 3;      // A stage: 64 rows x 64B chunks
    int brow = t >> 1, bhalf = t & 1;   // B stage: 128 rows x 128B halves
    int c = c0 + arow;

    for (int term = 0; term < 4; ++term) {
        const bf16* src;
        if (term == 0)      src = ops16 + ((size_t)(b*CC + c)) * DD;
        else if (term == 3) src = Oatt  + ((size_t)(b*CC + c)) * DD;
        else {
            int cc = min(c, CC - 3);
            int ridx = relations[((size_t)b*(CC-2) + cc)*2 + (term - 1)];
            src = ops16 + ((size_t)(b*CC) + ridx) * DD;
        }
        const uint4* s4 = (const uint4*)(src + aq*32);
        uint4* d4 = (uint4*)&Abuf[arow*136 + aq*32];
        #pragma unroll
        for (int ii = 0; ii < 4; ++ii) d4[ii] = s4[ii];

        const uint4* bs = (const uint4*)(Bsrc[term] + brow*128 + bhalf*64);
        uint4* bd = (uint4*)&Bbuf[brow*136 + bhalf*64];
        #pragma unroll
        for (int ii = 0; ii < 8; ++ii) bd[ii] = bs[ii];
        __syncthreads();

        #pragma unroll
        for (int kc = 0; kc < 4; ++kc) {
            bf16x8 bfr[2];
            #pragma unroll
            for (int cb = 0; cb < 2; ++cb)
                bfr[cb] = *(const bf16x8*)&Bbuf[(w*32 + cb*16 + m)*136 + kc*32 + q*8];
            #pragma unroll
            for (int rb = 0; rb < 4; ++rb) {
                bf16x8 afr = *(const bf16x8*)&Abuf[(rb*16 + m)*136 + kc*32 + q*8];
                acc[rb][0] = MFMA16(afr, bfr[0], acc[rb][0]);
                acc[rb][1] = MFMA16(afr, bfr[1], acc[rb][1]);
            }
        }
        __syncthreads();
    }
    #pragma unroll
    for (int cb = 0; cb < 2; ++cb) {
        int col = w*32 + cb*16 + m;
        float bias = BBM[col];
        #pragma unroll
        for (int rb = 0; rb < 4; ++rb) {
            #pragma unroll
            for (int r = 0; r < 4; ++r) {
                int cg = c0 + rb*16 + q*4 + r;
                if (cg < CC - 2)
                    out[((size_t)(b*CC) + cg)*DD + col] = acc[rb][cb][r] + bias;
            }
        }
    }
}

// =====================================================================
// Kernel EDGE: rows 2046 (begin) / 2047 (end). Output f32.
//   out = mean(gather(ops,idx)) @ (W_{b/e}@Wm2a) + O_att[row]@Wc + BB{B/E}
// =====================================================================
__global__ __launch_bounds__(128) void k_edge(
    const bf16* __restrict__ ops16, const int* __restrict__ begins,
    const int* __restrict__ ends, const bf16* __restrict__ Oatt,
    const bf16* __restrict__ GBT, const bf16* __restrict__ GET,
    const bf16* __restrict__ WCT, const float* __restrict__ BBB,
    const float* __restrict__ BBE, float* __restrict__ out)
{
    __shared__ float meanv[128];
    int b = blockIdx.x >> 1, which = blockIdx.x & 1;
    int t = threadIdx.x;
    const int* idx = which ? (ends + b*JJN) : (begins + b*JJN);
    const bf16* opsb = ops16 + (size_t)b * CC * DD;
    float s = 0.f;
    for (int j = 0; j < JJN; ++j) {
        int r = idx[j];
        s += (float)opsb[(size_t)r*DD + t];
    }
    meanv[t] = s * (1.0f / (float)JJN);
    __syncthreads();
    const bf16* G  = which ? GET : GBT;
    const float* Bv = which ? BBE : BBB;
    const bf16* orow = Oatt + ((size_t)b*CC + (CC - 2 + which)) * DD;
    float a = Bv[t];
    const bf16* gr = G + t*128;
    const bf16* wr = WCT + t*128;
    for (int d = 0; d < 128; ++d) {
        a += meanv[d] * (float)gr[d];
        a += (float)orow[d] * (float)wr[d];
    }
    out[((size_t)b*CC + (CC - 2 + which))*DD + t] = a;
}

// =====================================================================
extern "C" void kernel_launch(void* const* d_in, const int* in_sizes, int n_in,
                              void* d_out, int out_size, void* d_ws, size_t ws_size,
                              hipStream_t stream)
{
    const float* ops      = (const float*)d_in[0];
    const int*  relations = (const int*)d_in[1];
    const int*  begins    = (const int*)d_in[2];
    const int*  ends      = (const int*)d_in[3];
    const float* mask     = (const float*)d_in[4];
    const float* Wbegin   = (const float*)d_in[5];
    const float* bbegin   = (const float*)d_in[6];
    const float* Wend     = (const float*)d_in[7];
    const float* bend     = (const float*)d_in[8];
    const float* Wmix3    = (const float*)d_in[9];
    const float* bmix3    = (const float*)d_in[10];
    const float* Wqkv     = (const float*)d_in[11];
    const float* bqkv     = (const float*)d_in[12];
    const float* wscore   = (const float*)d_in[13];
    const float* bscore   = (const float*)d_in[14];
    const float* Wout     = (const float*)d_in[15];
    const float* bout     = (const float*)d_in[16];
    const float* Wmix2    = (const float*)d_in[17];
    const float* bmix2    = (const float*)d_in[18];
    float* outp = (float*)d_out;

    char* ws = (char*)d_ws;
    bf16*  VT    = (bf16*)(ws + WS_VT);
    bf16*  Oatt  = (bf16*)(ws + WS_OATT);
    bf16*  OPS16 = (bf16*)(ws + WS_OPS16);
    float* sqf   = (float*)(ws + WS_SQF);
    float* skf   = (float*)(ws + WS_SKF);
    bf16*  G1T   = (bf16*)(ws + WS_G1T);
    bf16*  G2T   = (bf16*)(ws + WS_G2T);
    bf16*  G3T   = (bf16*)(ws + WS_G3T);
    bf16*  WCT   = (bf16*)(ws + WS_WCT);
    bf16*  GBT   = (bf16*)(ws + WS_GBT);
    bf16*  GET   = (bf16*)(ws + WS_GET);
    bf16*  UQK   = (bf16*)(ws + WS_UQK);
    float* BBM   = (float*)(ws + WS_BBM);
    float* BBB   = (float*)(ws + WS_BBB);
    float* BBE   = (float*)(ws + WS_BBE);
    float* SC    = (float*)(ws + WS_SC);

    k_prepcast<<<dim3(1121), dim3(256), 0, stream>>>(
        ops, OPS16,
        Wmix3, Wmix2, Wout, Wbegin, Wend, Wqkv, bqkv, wscore, bscore,
        bmix3, bout, bmix2, bbegin, bend,
        G1T, G2T, G3T, WCT, GBT, GET, UQK, BBM, BBB, BBE, SC);

    k_v<<<dim3(128), dim3(256), 0, stream>>>(
        OPS16, Wqkv, bqkv, UQK, SC, VT, sqf, skf);

    k_att<<<dim3(1024), dim3(256), 0, stream>>>(
        mask, VT, sqf, skf, Oatt);

    k_epi<<<dim3(256), dim3(256), 0, stream>>>(
        OPS16, relations, Oatt, G1T, G2T, G3T, WCT, BBM, outp);

    k_edge<<<dim3(16), dim3(128), 0, stream>>>(
        OPS16, begins, ends, Oatt, GBT, GET, WCT, BBB, BBE, outp);
}

// Round 4
// 312.970 us; speedup vs baseline: 1.1183x; 1.0857x over previous
//
#include <hip/hip_runtime.h>
#include <cstddef>

typedef __bf16 bf16;
typedef __bf16 bf16x4 __attribute__((ext_vector_type(4)));
typedef __bf16 bf16x8 __attribute__((ext_vector_type(8)));
typedef float  f32x4  __attribute__((ext_vector_type(4)));

#define MFMA16(a, b, c) __builtin_amdgcn_mfma_f32_16x16x32_bf16((a), (b), (c), 0, 0, 0)

// ---------------- constants ----------------
#define BB 8
#define CC 2048
#define DD 128
#define JJN 128

// ws layout (bytes)
#define WS_PK    ((size_t)0)          // bf16 [8][64jc][8nb][4q][16m][8e] = [8][256K]
#define WS_OATT  ((size_t)4194304)    // bf16 [8][2048][128]
#define WS_OPS16 ((size_t)8388608)    // bf16 [8][2048][128]
#define WS_SQF   ((size_t)12582912)   // f32  [8][2048]
#define WS_SKF   ((size_t)12648448)   // f32  [8][2048]
#define WS_G1T   ((size_t)12713984)   // bf16 [128][128] (transposed: [e][d])
#define WS_G2T   ((size_t)12746752)
#define WS_G3T   ((size_t)12779520)
#define WS_WCT   ((size_t)12812288)
#define WS_GBT   ((size_t)12845056)
#define WS_GET   ((size_t)12877824)
#define WS_UQK   ((size_t)12910592)   // bf16 [2][128]
#define WS_BBM   ((size_t)12911104)   // f32 [128]
#define WS_BBB   ((size_t)12911616)   // f32 [128]
#define WS_BBE   ((size_t)12912128)   // f32 [128]
#define WS_SC    ((size_t)12912640)   // f32 [2]

// =====================================================================
// Kernel PREPCAST: blocks 0..1023 cast ops f32->bf16; 1024..1119 fold
// weight products; block 1120 vector folds.
// =====================================================================
__global__ __launch_bounds__(256) void k_prepcast(
    const float* __restrict__ ops, bf16* __restrict__ ops16,
    const float* __restrict__ Wmix3, const float* __restrict__ Wmix2,
    const float* __restrict__ Wout,  const float* __restrict__ Wbegin,
    const float* __restrict__ Wend,  const float* __restrict__ Wqkv,
    const float* __restrict__ bqkv,  const float* __restrict__ wscore,
    const float* __restrict__ bscore,const float* __restrict__ bmix3,
    const float* __restrict__ bout,  const float* __restrict__ bmix2,
    const float* __restrict__ bbegin,const float* __restrict__ bend,
    bf16* __restrict__ G1T, bf16* __restrict__ G2T, bf16* __restrict__ G3T,
    bf16* __restrict__ WCT, bf16* __restrict__ GBT, bf16* __restrict__ GET,
    bf16* __restrict__ uqk, float* __restrict__ BBM, float* __restrict__ BBB,
    float* __restrict__ BBE, float* __restrict__ sc)
{
    __shared__ bf16  LshT[128 * 132];
    __shared__ float Rsh[128 * 8];
    int wg = blockIdx.x;
    int t  = threadIdx.x;

    if (wg < 1024) {
        size_t i = (size_t)wg * 256 + t;
        f32x4 a = *(const f32x4*)(ops + i * 8);
        f32x4 b = *(const f32x4*)(ops + i * 8 + 4);
        bf16x8 o;
        #pragma unroll
        for (int e = 0; e < 4; ++e) { o[e] = (bf16)a[e]; o[4 + e] = (bf16)b[e]; }
        *(bf16x8*)(ops16 + i * 8) = o;
        return;
    }
    if (wg < 1120) {
        int id  = wg - 1024;
        int mat = id >> 4, sub = id & 15;
        const float* L; const float* R; bf16* O;
        switch (mat) {
            case 0: L = Wmix3;           R = Wmix2;           O = G1T; break;
            case 1: L = Wmix3 + 128*128; R = Wmix2;           O = G2T; break;
            case 2: L = Wmix3 + 256*128; R = Wmix2;           O = G3T; break;
            case 3: L = Wout;            R = Wmix2 + 128*128; O = WCT; break;
            case 4: L = Wbegin;          R = Wmix2;           O = GBT; break;
            default:L = Wend;            R = Wmix2;           O = GET; break;
        }
        int e0 = sub * 8;
        #pragma unroll
        for (int pass = 0; pass < 16; ++pass) {
            int idx = pass * 256 + t;
            int d   = idx >> 5;
            int f0  = (idx & 31) * 4;
            f32x4 v = *(const f32x4*)(L + d * 128 + f0);
            #pragma unroll
            for (int jj = 0; jj < 4; ++jj)
                LshT[(f0 + jj) * 132 + d] = (bf16)v[jj];
        }
        #pragma unroll
        for (int pass = 0; pass < 4; ++pass) {
            int idx = pass * 256 + t;
            int f   = idx >> 3;
            int ee  = idx & 7;
            Rsh[f * 8 + ee] = R[f * 128 + e0 + ee];
        }
        __syncthreads();
        int ee = t >> 5;
        int e  = e0 + ee;
        int d0 = (t & 31) * 4;
        float s[4] = {0.f, 0.f, 0.f, 0.f};
        for (int f = 0; f < 128; ++f) {
            bf16x4 lv = *(const bf16x4*)&LshT[f * 132 + d0];
            float rv = Rsh[f * 8 + ee];
            #pragma unroll
            for (int dd = 0; dd < 4; ++dd)
                s[dd] += (float)lv[dd] * rv;
        }
        #pragma unroll
        for (int dd = 0; dd < 4; ++dd)
            O[e * 128 + d0 + dd] = (bf16)s[dd];
        return;
    }
    if (t < 128) {
        int d = t;
        float su = 0.f, sk_ = 0.f;
        for (int e2 = 0; e2 < 128; ++e2) {
            su  += Wqkv[d*384 + e2]       * wscore[e2];
            sk_ += Wqkv[d*384 + 128 + e2] * wscore[128 + e2];
        }
        uqk[d]       = (bf16)su;
        uqk[128 + d] = (bf16)sk_;
        int e = d;
        float bm = 0.f, bon = 0.f, bb_ = 0.f, be_ = 0.f;
        for (int f = 0; f < 128; ++f) {
            float w2a = Wmix2[f*128 + e];
            float w2b = Wmix2[(128+f)*128 + e];
            bm  += bmix3[f]  * w2a;
            bon += bout[f]   * w2b;
            bb_ += bbegin[f] * w2a;
            be_ += bend[f]   * w2a;
        }
        float bm2 = bmix2[e];
        BBM[e] = bm  + bon + bm2;
        BBB[e] = bb_ + bon + bm2;
        BBE[e] = be_ + bon + bm2;
    } else if (t == 128) {
        float cq = 0.f, ck = 0.f;
        for (int e2 = 0; e2 < 128; ++e2) {
            cq += bqkv[e2]       * wscore[e2];
            ck += bqkv[128 + e2] * wscore[128 + e2];
        }
        sc[0] = cq + bscore[0];
        sc[1] = ck;
    }
}

// =====================================================================
// Kernel V: V = ops@Wv + b_v, stored in MFMA-B-fragment-packed layout
//   PK[b][jc][nb][q][m][e]  (j = jc*32 + q*8 + e ; n = nb*16 + m)
// so k_att's B-fragment loads are wave-contiguous. Rows 128/129 of the
// A-operand give sq/sk for free.
// =====================================================================
__global__ __launch_bounds__(256) void k_v(
    const bf16* __restrict__ ops16, const float* __restrict__ Wqkv,
    const float* __restrict__ bqkv, const bf16* __restrict__ uqk,
    const float* __restrict__ sc,
    bf16* __restrict__ PK, float* __restrict__ sqf, float* __restrict__ skf)
{
    __shared__ bf16 A[144 * 136];
    int b  = blockIdx.x >> 4;
    int jt = (blockIdx.x & 15) * 128;
    int t  = threadIdx.x;
    #pragma unroll
    for (int pass = 0; pass < 16; ++pass) {
        int idx = pass * 256 + t;
        int d   = idx >> 5;
        int n0  = (idx & 31) * 4;
        f32x4 v = *(const f32x4*)(Wqkv + d*384 + 256 + n0);
        #pragma unroll
        for (int jj = 0; jj < 4; ++jj)
            A[(n0 + jj)*136 + d] = (bf16)v[jj];
    }
    {
        int row = t >> 7, col = t & 127;
        A[(128 + row)*136 + col] = uqk[row*128 + col];
    }
    for (int idx = t; idx < 14*136; idx += 256)
        A[130*136 + idx] = (bf16)0.f;
    __syncthreads();

    int lane = t & 63, w = t >> 6;
    int m = lane & 15, q = lane >> 4;
    f32x4 acc[9][2];
    #pragma unroll
    for (int rb = 0; rb < 9; ++rb)
        #pragma unroll
        for (int cb = 0; cb < 2; ++cb)
            acc[rb][cb] = {0.f, 0.f, 0.f, 0.f};

    const bf16* opsb = ops16 + (size_t)b * CC * DD;
    #pragma unroll
    for (int kc = 0; kc < 4; ++kc) {
        bf16x8 bfr[2];
        #pragma unroll
        for (int cb = 0; cb < 2; ++cb) {
            int j = jt + w*32 + cb*16 + m;
            bfr[cb] = *(const bf16x8*)(opsb + (size_t)j*DD + kc*32 + q*8);
        }
        #pragma unroll
        for (int rb = 0; rb < 9; ++rb) {
            bf16x8 afr = *(const bf16x8*)&A[(rb*16 + m)*136 + kc*32 + q*8];
            acc[rb][0] = MFMA16(afr, bfr[0], acc[rb][0]);
            acc[rb][1] = MFMA16(afr, bfr[1], acc[rb][1]);
        }
    }
    float cqb = sc[0], ckv = sc[1];
    bf16* pkb = PK + (size_t)b * DD * CC;
    #pragma unroll
    for (int cb = 0; cb < 2; ++cb) {
        int j  = jt + w*32 + cb*16 + m;
        int jc = j >> 5, jl = j & 31;
        int qq = jl >> 3, e = jl & 7;
        #pragma unroll
        for (int rb = 0; rb < 8; ++rb) {
            #pragma unroll
            for (int r = 0; r < 4; ++r) {
                float v = acc[rb][cb][r] + bqkv[256 + rb*16 + q*4 + r];
                pkb[((size_t)(((jc*8 + rb)*4 + qq)*16 + (q*4 + r)))*8 + e] = (bf16)v;
            }
        }
        if (q == 0) {
            sqf[b*CC + j] = acc[8][cb][0] + cqb;
            skf[b*CC + j] = acc[8][cb][1] + ckv;
        }
    }
}

// =====================================================================
// Kernel ATT: streaming softmax-GEMM, all global loads wave-contiguous.
// Block = 16-row i-tile, wave w owns j-quarter [w*512, (w+1)*512).
// Mask staged (f32->bf16) through per-wave double-buffered LDS in 64-j
// chunks; sk staged once per wave; V read from PK (contiguous).
// =====================================================================
struct MaskLd { f32x4 v[4]; };

__device__ __forceinline__ MaskLd stage_load(const float* __restrict__ mrow0,
                                             int st, int lane)
{
    MaskLd L;
    int rr0 = lane >> 4, cc = (lane & 15) * 4;
    const float* src = mrow0 + st * 64 + cc;
    #pragma unroll
    for (int k = 0; k < 4; ++k)
        L.v[k] = __builtin_nontemporal_load(
            (const f32x4*)(src + ((size_t)(rr0 + k * 4)) * CC));
    return L;
}

__device__ __forceinline__ void stage_write(const MaskLd& L, bf16* mb,
                                            int st, int lane)
{
    int rr0 = lane >> 4, cc = (lane & 15) * 4;
    bf16* dst = mb + (st & 1) * 1152;            // [16 rows][72]
    #pragma unroll
    for (int k = 0; k < 4; ++k) {
        bf16x4 o;
        #pragma unroll
        for (int e = 0; e < 4; ++e) o[e] = (bf16)L.v[k][e];
        *(bf16x4*)(dst + (rr0 + k * 4) * 72 + cc) = o;
    }
}

__device__ __forceinline__ void load_vb(const bf16* __restrict__ pkb, int jc,
                                        int q, int m, bf16x8 vb[8])
{
    #pragma unroll
    for (int nb = 0; nb < 8; ++nb)
        vb[nb] = *(const bf16x8*)(pkb + ((size_t)(((jc*8 + nb)*4 + q)*16 + m)) * 8);
}

__device__ __forceinline__ void substep(const bf16* mb, const float* skb,
    int st, int sub, int q, int m, float sq, const bf16x8 vb[8],
    float& lsum, f32x4 acc[8])
{
    bf16x8 mk = *(const bf16x8*)(mb + (st & 1) * 1152 + m * 72 + sub * 32 + q * 8);
    int jo = st * 64 + sub * 32 + q * 8;
    f32x4 s0 = *(const f32x4*)(skb + jo);
    f32x4 s1 = *(const f32x4*)(skb + jo + 4);
    float sks[8] = {s0[0], s0[1], s0[2], s0[3], s1[0], s1[1], s1[2], s1[3]};
    bf16x8 a;
    #pragma unroll
    for (int e = 0; e < 8; ++e) {
        float tv = sq + sks[e];
        float lr = fmaxf(tv, 0.01f * tv);
        float z  = lr * (float)mk[e];
        float p  = __expf(z);
        lsum += p;
        a[e] = (bf16)p;
    }
    #pragma unroll
    for (int nb = 0; nb < 8; ++nb)
        acc[nb] = MFMA16(a, vb[nb], acc[nb]);
}

__global__ __launch_bounds__(256, 3) void k_att(
    const float* __restrict__ mask, const bf16* __restrict__ PK,
    const float* __restrict__ sqf, const float* __restrict__ skf,
    bf16* __restrict__ Oatt)
{
    __shared__ __align__(16) char smem[34048];
    int t    = threadIdx.x;
    int lane = t & 63, w = t >> 6;
    int b    = blockIdx.x & 7;                 // XCD-locality: same b per XCD
    int i0   = (blockIdx.x >> 3) << 4;
    int m = lane & 15, q = lane >> 4;

    bf16*  mbuf = (bf16*)(smem + w * 4608);            // 2 bufs x [16][72]
    float* skb  = (float*)(smem + 18432 + w * 2048);   // [512]

    {   // stage this wave's sk quarter
        const float* src = skf + b*CC + w*512;
        f32x4 v0 = *(const f32x4*)(src + lane*4);
        f32x4 v1 = *(const f32x4*)(src + 256 + lane*4);
        *(f32x4*)(skb + lane*4) = v0;
        *(f32x4*)(skb + 256 + lane*4) = v1;
    }
    float sq = sqf[b*CC + i0 + m];
    const float* mrow0 = mask + ((size_t)(b*CC + i0))*CC + w*512;
    const bf16*  pkb   = PK + (size_t)b * DD * CC;
    int jc0 = w * 16;

    f32x4 acc[8];
    #pragma unroll
    for (int nb = 0; nb < 8; ++nb) acc[nb] = {0.f, 0.f, 0.f, 0.f};
    float lsum = 0.f;

    MaskLd L0 = stage_load(mrow0, 0, lane);
    stage_write(L0, mbuf, 0, lane);
    bf16x8 vbA[8], vbB[8];
    load_vb(pkb, jc0, q, m, vbA);

    for (int st = 0; st < 8; ++st) {
        MaskLd Ln;
        if (st < 7) Ln = stage_load(mrow0, st + 1, lane);   // global, overlaps
        load_vb(pkb, jc0 + st*2 + 1, q, m, vbB);
        substep(mbuf, skb, st, 0, q, m, sq, vbA, lsum, acc);
        if (st < 7) load_vb(pkb, jc0 + st*2 + 2, q, m, vbA);
        substep(mbuf, skb, st, 1, q, m, sq, vbB, lsum, acc);
        if (st < 7) stage_write(Ln, mbuf, st + 1, lane);
    }

    __syncthreads();            // mask/sk LDS dead for ALL waves
    float* Osh = (float*)smem;                // [4*16][132]
    float* Lsh = (float*)(smem + 33792);      // [64]
    lsum += __shfl_xor(lsum, 16, 64);
    lsum += __shfl_xor(lsum, 32, 64);
    if (q == 0) Lsh[w*16 + m] = lsum;
    #pragma unroll
    for (int nb = 0; nb < 8; ++nb)
        #pragma unroll
        for (int r = 0; r < 4; ++r)
            Osh[(w*16 + q*4 + r)*132 + nb*16 + m] = acc[nb][r];
    __syncthreads();

    int r  = t >> 4;
    int c0 = (t & 15) * 8;
    float l = Lsh[r] + Lsh[16 + r] + Lsh[32 + r] + Lsh[48 + r];
    float inv = 1.0f / l;
    bf16x8 o;
    #pragma unroll
    for (int e = 0; e < 8; ++e) {
        float s = Osh[r*132 + c0 + e] + Osh[(16 + r)*132 + c0 + e]
                + Osh[(32 + r)*132 + c0 + e] + Osh[(48 + r)*132 + c0 + e];
        o[e] = (bf16)(s * inv);
    }
    *(bf16x8*)(Oatt + ((size_t)(b*CC) + i0 + r)*DD + c0) = o;
}

// =====================================================================
// Kernel EPI: out[c] = ops[c]@G1 + ops[pred]@G2 + ops[succ]@G3
//                    + O_att[c]@Wc + BBM, rows c < 2046.
// 512 wgs (b, 32-row tile) -> 2 blocks/CU.
// =====================================================================
__global__ __launch_bounds__(256) void k_epi(
    const bf16* __restrict__ ops16, const int* __restrict__ relations,
    const bf16* __restrict__ Oatt,
    const bf16* __restrict__ G1T, const bf16* __restrict__ G2T,
    const bf16* __restrict__ G3T, const bf16* __restrict__ WCT,
    const float* __restrict__ BBM, float* __restrict__ out)
{
    __shared__ bf16 Abuf[32 * 136];
    __shared__ bf16 Bbuf[128 * 136];
    int b  = blockIdx.x >> 6;
    int c0 = (blockIdx.x & 63) * 32;
    int t  = threadIdx.x;
    int lane = t & 63, w = t >> 6;
    int m = lane & 15, q = lane >> 4;

    f32x4 acc[2][2];
    #pragma unroll
    for (int rb = 0; rb < 2; ++rb)
        #pragma unroll
        for (int cb = 0; cb < 2; ++cb)
            acc[rb][cb] = {0.f, 0.f, 0.f, 0.f};

    const bf16* Bsrc[4] = {G1T, G2T, G3T, WCT};
    int arow = t >> 3, ao = (t & 7) * 16;    // A: 32 rows x 8 thr x 32 B
    int brow = t >> 1, bo = (t & 1) * 64;    // B: 128 rows x 2 thr x 128 B
    int c = c0 + arow;

    for (int term = 0; term < 4; ++term) {
        const bf16* src;
        if (term == 0)      src = ops16 + ((size_t)(b*CC + c)) * DD;
        else if (term == 3) src = Oatt  + ((size_t)(b*CC + c)) * DD;
        else {
            int ridx = relations[((size_t)b*(CC-2) + min(c, CC-3))*2 + (term - 1)];
            src = ops16 + ((size_t)(b*CC) + ridx) * DD;
        }
        *(uint4*)&Abuf[arow*136 + ao]     = *(const uint4*)(src + ao);
        *(uint4*)&Abuf[arow*136 + ao + 8] = *(const uint4*)(src + ao + 8);

        const uint4* bs = (const uint4*)(Bsrc[term] + brow*128 + bo);
        uint4* bd = (uint4*)&Bbuf[brow*136 + bo];
        #pragma unroll
        for (int ii = 0; ii < 8; ++ii) bd[ii] = bs[ii];
        __syncthreads();

        #pragma unroll
        for (int kc = 0; kc < 4; ++kc) {
            bf16x8 bfr[2];
            #pragma unroll
            for (int cb = 0; cb < 2; ++cb)
                bfr[cb] = *(const bf16x8*)&Bbuf[(w*32 + cb*16 + m)*136 + kc*32 + q*8];
            #pragma unroll
            for (int rb = 0; rb < 2; ++rb) {
                bf16x8 afr = *(const bf16x8*)&Abuf[(rb*16 + m)*136 + kc*32 + q*8];
                acc[rb][0] = MFMA16(afr, bfr[0], acc[rb][0]);
                acc[rb][1] = MFMA16(afr, bfr[1], acc[rb][1]);
            }
        }
        __syncthreads();
    }
    #pragma unroll
    for (int cb = 0; cb < 2; ++cb) {
        int col = w*32 + cb*16 + m;
        float bias = BBM[col];
        #pragma unroll
        for (int rb = 0; rb < 2; ++rb) {
            #pragma unroll
            for (int r = 0; r < 4; ++r) {
                int cg = c0 + rb*16 + q*4 + r;
                if (cg < CC - 2)
                    out[((size_t)(b*CC) + cg)*DD + col] = acc[rb][cb][r] + bias;
            }
        }
    }
}

// =====================================================================
// Kernel EDGE: rows 2046 (begin) / 2047 (end). Output f32.
// =====================================================================
__global__ __launch_bounds__(128) void k_edge(
    const bf16* __restrict__ ops16, const int* __restrict__ begins,
    const int* __restrict__ ends, const bf16* __restrict__ Oatt,
    const bf16* __restrict__ GBT, const bf16* __restrict__ GET,
    const bf16* __restrict__ WCT, const float* __restrict__ BBB,
    const float* __restrict__ BBE, float* __restrict__ out)
{
    __shared__ float meanv[128];
    int b = blockIdx.x >> 1, which = blockIdx.x & 1;
    int t = threadIdx.x;
    const int* idx = which ? (ends + b*JJN) : (begins + b*JJN);
    const bf16* opsb = ops16 + (size_t)b * CC * DD;
    float s = 0.f;
    for (int j = 0; j < JJN; ++j) {
        int r = idx[j];
        s += (float)opsb[(size_t)r*DD + t];
    }
    meanv[t] = s * (1.0f / (float)JJN);
    __syncthreads();
    const bf16* G  = which ? GET : GBT;
    const float* Bv = which ? BBE : BBB;
    const bf16* orow = Oatt + ((size_t)b*CC + (CC - 2 + which)) * DD;
    float a = Bv[t];
    const bf16* gr = G + t*128;
    const bf16* wr = WCT + t*128;
    for (int d = 0; d < 128; ++d) {
        a += meanv[d] * (float)gr[d];
        a += (float)orow[d] * (float)wr[d];
    }
    out[((size_t)b*CC + (CC - 2 + which))*DD + t] = a;
}

// =====================================================================
extern "C" void kernel_launch(void* const* d_in, const int* in_sizes, int n_in,
                              void* d_out, int out_size, void* d_ws, size_t ws_size,
                              hipStream_t stream)
{
    const float* ops      = (const float*)d_in[0];
    const int*  relations = (const int*)d_in[1];
    const int*  begins    = (const int*)d_in[2];
    const int*  ends      = (const int*)d_in[3];
    const float* mask     = (const float*)d_in[4];
    const float* Wbegin   = (const float*)d_in[5];
    const float* bbegin   = (const float*)d_in[6];
    const float* Wend     = (const float*)d_in[7];
    const float* bend     = (const float*)d_in[8];
    const float* Wmix3    = (const float*)d_in[9];
    const float* bmix3    = (const float*)d_in[10];
    const float* Wqkv     = (const float*)d_in[11];
    const float* bqkv     = (const float*)d_in[12];
    const float* wscore   = (const float*)d_in[13];
    const float* bscore   = (const float*)d_in[14];
    const float* Wout     = (const float*)d_in[15];
    const float* bout     = (const float*)d_in[16];
    const float* Wmix2    = (const float*)d_in[17];
    const float* bmix2    = (const float*)d_in[18];
    float* outp = (float*)d_out;

    char* ws = (char*)d_ws;
    bf16*  PK    = (bf16*)(ws + WS_PK);
    bf16*  Oatt  = (bf16*)(ws + WS_OATT);
    bf16*  OPS16 = (bf16*)(ws + WS_OPS16);
    float* sqf   = (float*)(ws + WS_SQF);
    float* skf   = (float*)(ws + WS_SKF);
    bf16*  G1T   = (bf16*)(ws + WS_G1T);
    bf16*  G2T   = (bf16*)(ws + WS_G2T);
    bf16*  G3T   = (bf16*)(ws + WS_G3T);
    bf16*  WCT   = (bf16*)(ws + WS_WCT);
    bf16*  GBT   = (bf16*)(ws + WS_GBT);
    bf16*  GET   = (bf16*)(ws + WS_GET);
    bf16*  UQK   = (bf16*)(ws + WS_UQK);
    float* BBM   = (float*)(ws + WS_BBM);
    float* BBB   = (float*)(ws + WS_BBB);
    float* BBE   = (float*)(ws + WS_BBE);
    float* SC    = (float*)(ws + WS_SC);

    k_prepcast<<<dim3(1121), dim3(256), 0, stream>>>(
        ops, OPS16,
        Wmix3, Wmix2, Wout, Wbegin, Wend, Wqkv, bqkv, wscore, bscore,
        bmix3, bout, bmix2, bbegin, bend,
        G1T, G2T, G3T, WCT, GBT, GET, UQK, BBM, BBB, BBE, SC);

    k_v<<<dim3(128), dim3(256), 0, stream>>>(
        OPS16, Wqkv, bqkv, UQK, SC, PK, sqf, skf);

    k_att<<<dim3(1024), dim3(256), 0, stream>>>(
        mask, PK, sqf, skf, Oatt);

    k_epi<<<dim3(512), dim3(256), 0, stream>>>(
        OPS16, relations, Oatt, G1T, G2T, G3T, WCT, BBM, outp);

    k_edge<<<dim3(16), dim3(128), 0, stream>>>(
        OPS16, begins, ends, Oatt, GBT, GET, WCT, BBB, BBE, outp);
}

// Round 6
// 296.175 us; speedup vs baseline: 1.1817x; 1.0567x over previous
//
#include <hip/hip_runtime.h>
#include <cstddef>

typedef __bf16 bf16;
typedef __bf16 bf16x4 __attribute__((ext_vector_type(4)));
typedef __bf16 bf16x8 __attribute__((ext_vector_type(8)));
typedef float  f32x4  __attribute__((ext_vector_type(4)));

#define MFMA16(a, b, c) __builtin_amdgcn_mfma_f32_16x16x32_bf16((a), (b), (c), 0, 0, 0)

// ---------------- constants ----------------
#define BB 8
#define CC 2048
#define DD 128
#define JJN 128

// ws layout (bytes)
#define WS_PK    ((size_t)0)          // bf16 [8][64jc][8nb][4q][16m][8e]
#define WS_OATT  ((size_t)4194304)    // bf16 [8][2048][128]
#define WS_OPS16 ((size_t)8388608)    // bf16 [8][2048][128]
#define WS_SQF   ((size_t)12582912)   // f32  [8][2048]
#define WS_SKF   ((size_t)12648448)   // f32  [8][2048]
#define WS_G1T   ((size_t)12713984)   // bf16 [128][128] (transposed: [e][d])
#define WS_G2T   ((size_t)12746752)
#define WS_G3T   ((size_t)12779520)
#define WS_WCT   ((size_t)12812288)
#define WS_GBT   ((size_t)12845056)
#define WS_GET   ((size_t)12877824)
#define WS_UQK   ((size_t)12910592)   // bf16 [2][128]
#define WS_BBM   ((size_t)12911104)   // f32 [128]
#define WS_BBB   ((size_t)12911616)   // f32 [128]
#define WS_BBE   ((size_t)12912128)   // f32 [128]
#define WS_SC    ((size_t)12912640)   // f32 [2]

// =====================================================================
// Kernel PREPCAST: blocks 0..1023 cast ops f32->bf16; 1024..1119 fold
// weight products; block 1120 vector folds.
// =====================================================================
__global__ __launch_bounds__(256) void k_prepcast(
    const float* __restrict__ ops, bf16* __restrict__ ops16,
    const float* __restrict__ Wmix3, const float* __restrict__ Wmix2,
    const float* __restrict__ Wout,  const float* __restrict__ Wbegin,
    const float* __restrict__ Wend,  const float* __restrict__ Wqkv,
    const float* __restrict__ bqkv,  const float* __restrict__ wscore,
    const float* __restrict__ bscore,const float* __restrict__ bmix3,
    const float* __restrict__ bout,  const float* __restrict__ bmix2,
    const float* __restrict__ bbegin,const float* __restrict__ bend,
    bf16* __restrict__ G1T, bf16* __restrict__ G2T, bf16* __restrict__ G3T,
    bf16* __restrict__ WCT, bf16* __restrict__ GBT, bf16* __restrict__ GET,
    bf16* __restrict__ uqk, float* __restrict__ BBM, float* __restrict__ BBB,
    float* __restrict__ BBE, float* __restrict__ sc)
{
    __shared__ bf16  LshT[128 * 132];
    __shared__ float Rsh[128 * 8];
    int wg = blockIdx.x;
    int t  = threadIdx.x;

    if (wg < 1024) {
        size_t i = (size_t)wg * 256 + t;
        f32x4 a = *(const f32x4*)(ops + i * 8);
        f32x4 b = *(const f32x4*)(ops + i * 8 + 4);
        bf16x8 o;
        #pragma unroll
        for (int e = 0; e < 4; ++e) { o[e] = (bf16)a[e]; o[4 + e] = (bf16)b[e]; }
        *(bf16x8*)(ops16 + i * 8) = o;
        return;
    }
    if (wg < 1120) {
        int id  = wg - 1024;
        int mat = id >> 4, sub = id & 15;
        const float* L; const float* R; bf16* O;
        switch (mat) {
            case 0: L = Wmix3;           R = Wmix2;           O = G1T; break;
            case 1: L = Wmix3 + 128*128; R = Wmix2;           O = G2T; break;
            case 2: L = Wmix3 + 256*128; R = Wmix2;           O = G3T; break;
            case 3: L = Wout;            R = Wmix2 + 128*128; O = WCT; break;
            case 4: L = Wbegin;          R = Wmix2;           O = GBT; break;
            default:L = Wend;            R = Wmix2;           O = GET; break;
        }
        int e0 = sub * 8;
        #pragma unroll
        for (int pass = 0; pass < 16; ++pass) {
            int idx = pass * 256 + t;
            int d   = idx >> 5;
            int f0  = (idx & 31) * 4;
            f32x4 v = *(const f32x4*)(L + d * 128 + f0);
            #pragma unroll
            for (int jj = 0; jj < 4; ++jj)
                LshT[(f0 + jj) * 132 + d] = (bf16)v[jj];
        }
        #pragma unroll
        for (int pass = 0; pass < 4; ++pass) {
            int idx = pass * 256 + t;
            int f   = idx >> 3;
            int ee  = idx & 7;
            Rsh[f * 8 + ee] = R[f * 128 + e0 + ee];
        }
        __syncthreads();
        int ee = t >> 5;
        int e  = e0 + ee;
        int d0 = (t & 31) * 4;
        float s[4] = {0.f, 0.f, 0.f, 0.f};
        for (int f = 0; f < 128; ++f) {
            bf16x4 lv = *(const bf16x4*)&LshT[f * 132 + d0];
            float rv = Rsh[f * 8 + ee];
            #pragma unroll
            for (int dd = 0; dd < 4; ++dd)
                s[dd] += (float)lv[dd] * rv;
        }
        #pragma unroll
        for (int dd = 0; dd < 4; ++dd)
            O[e * 128 + d0 + dd] = (bf16)s[dd];
        return;
    }
    if (t < 128) {
        int d = t;
        float su = 0.f, sk_ = 0.f;
        for (int e2 = 0; e2 < 128; ++e2) {
            su  += Wqkv[d*384 + e2]       * wscore[e2];
            sk_ += Wqkv[d*384 + 128 + e2] * wscore[128 + e2];
        }
        uqk[d]       = (bf16)su;
        uqk[128 + d] = (bf16)sk_;
        int e = d;
        float bm = 0.f, bon = 0.f, bb_ = 0.f, be_ = 0.f;
        for (int f = 0; f < 128; ++f) {
            float w2a = Wmix2[f*128 + e];
            float w2b = Wmix2[(128+f)*128 + e];
            bm  += bmix3[f]  * w2a;
            bon += bout[f]   * w2b;
            bb_ += bbegin[f] * w2a;
            be_ += bend[f]   * w2a;
        }
        float bm2 = bmix2[e];
        BBM[e] = bm  + bon + bm2;
        BBB[e] = bb_ + bon + bm2;
        BBE[e] = be_ + bon + bm2;
    } else if (t == 128) {
        float cq = 0.f, ck = 0.f;
        for (int e2 = 0; e2 < 128; ++e2) {
            cq += bqkv[e2]       * wscore[e2];
            ck += bqkv[128 + e2] * wscore[128 + e2];
        }
        sc[0] = cq + bscore[0];
        sc[1] = ck;
    }
}

// =====================================================================
// Kernel V: V = ops@Wv + b_v in PK layout. Epilogue scatters through
// LDS (reusing the A-tile region) and stores PK with contiguous dwordx4.
//   PK[b] idx(j,n) = (j>>5)*4096 + (n>>4)*512 + ((j&31)>>3)*128
//                   + (n&15)*8 + (j&7)
// =====================================================================
__global__ __launch_bounds__(256) void k_v(
    const bf16* __restrict__ ops16, const float* __restrict__ Wqkv,
    const float* __restrict__ bqkv, const bf16* __restrict__ uqk,
    const float* __restrict__ sc,
    bf16* __restrict__ PK, float* __restrict__ sqf, float* __restrict__ skf)
{
    __shared__ bf16 A[144 * 136];     // also reused as 32 KB pack buffer
    int b  = blockIdx.x >> 4;
    int jt = (blockIdx.x & 15) * 128;
    int t  = threadIdx.x;
    #pragma unroll
    for (int pass = 0; pass < 16; ++pass) {
        int idx = pass * 256 + t;
        int d   = idx >> 5;
        int n0  = (idx & 31) * 4;
        f32x4 v = *(const f32x4*)(Wqkv + d*384 + 256 + n0);
        #pragma unroll
        for (int jj = 0; jj < 4; ++jj)
            A[(n0 + jj)*136 + d] = (bf16)v[jj];
    }
    {
        int row = t >> 7, col = t & 127;
        A[(128 + row)*136 + col] = uqk[row*128 + col];
    }
    for (int idx = t; idx < 14*136; idx += 256)
        A[130*136 + idx] = (bf16)0.f;
    __syncthreads();

    int lane = t & 63, w = t >> 6;
    int m = lane & 15, q = lane >> 4;
    f32x4 acc[9][2];
    #pragma unroll
    for (int rb = 0; rb < 9; ++rb)
        #pragma unroll
        for (int cb = 0; cb < 2; ++cb)
            acc[rb][cb] = {0.f, 0.f, 0.f, 0.f};

    const bf16* opsb = ops16 + (size_t)b * CC * DD;
    #pragma unroll
    for (int kc = 0; kc < 4; ++kc) {
        bf16x8 bfr[2];
        #pragma unroll
        for (int cb = 0; cb < 2; ++cb) {
            int j = jt + w*32 + cb*16 + m;
            bfr[cb] = *(const bf16x8*)(opsb + (size_t)j*DD + kc*32 + q*8);
        }
        #pragma unroll
        for (int rb = 0; rb < 9; ++rb) {
            bf16x8 afr = *(const bf16x8*)&A[(rb*16 + m)*136 + kc*32 + q*8];
            acc[rb][0] = MFMA16(afr, bfr[0], acc[rb][0]);
            acc[rb][1] = MFMA16(afr, bfr[1], acc[rb][1]);
        }
    }
    float cqb = sc[0], ckv = sc[1];
    // sq/sk from A-rows 128/129
    #pragma unroll
    for (int cb = 0; cb < 2; ++cb) {
        int j = jt + w*32 + cb*16 + m;
        if (q == 0) {
            sqf[b*CC + j] = acc[8][cb][0] + cqb;
            skf[b*CC + j] = acc[8][cb][1] + ckv;
        }
    }
    __syncthreads();               // all waves done reading A
    bf16* pack = A;                // 16384 elems = 32 KB
    #pragma unroll
    for (int cb = 0; cb < 2; ++cb) {
        int qq_base = cb*2 + (m>>3);
        int e       = m & 7;
        #pragma unroll
        for (int rb = 0; rb < 8; ++rb) {
            #pragma unroll
            for (int r = 0; r < 4; ++r) {
                float v = acc[rb][cb][r] + bqkv[256 + rb*16 + q*4 + r];
                pack[w*4096 + rb*512 + qq_base*128 + (q*4+r)*8 + e] = (bf16)v;
            }
        }
    }
    __syncthreads();
    bf16* pkb = PK + (size_t)b * DD * CC + (size_t)jt * 128;
    #pragma unroll
    for (int pass = 0; pass < 8; ++pass) {
        int lidx = pass * 256 + t;
        *(uint4*)(pkb + (size_t)lidx * 8) = *(const uint4*)&pack[lidx * 8];
    }
}

// =====================================================================
// Kernel ATT: streaming softmax-GEMM. Block = 16-row i-tile, wave w
// owns j-quarter (512 j = 8 steps of 64). Mask pipeline: 3 in-flight
// register buffers + triple-buffered LDS stage (~2-step vmcnt slack).
// =====================================================================
struct MaskLd { f32x4 v[4]; };

__device__ __forceinline__ MaskLd stage_load(const float* __restrict__ mrow0,
                                             int st, int lane)
{
    MaskLd L;
    int rr0 = lane >> 4, cc = (lane & 15) * 4;
    const float* src = mrow0 + st * 64 + cc;
    #pragma unroll
    for (int k = 0; k < 4; ++k)
        L.v[k] = __builtin_nontemporal_load(
            (const f32x4*)(src + ((size_t)(rr0 + k * 4)) * CC));
    return L;
}

__device__ __forceinline__ void stage_write(const MaskLd& L, bf16* mb,
                                            int buf, int lane)
{
    int rr0 = lane >> 4, cc = (lane & 15) * 4;
    bf16* dst = mb + buf * 1152;                 // [16 rows][72]
    #pragma unroll
    for (int k = 0; k < 4; ++k) {
        bf16x4 o;
        #pragma unroll
        for (int e = 0; e < 4; ++e) o[e] = (bf16)L.v[k][e];
        *(bf16x4*)(dst + (rr0 + k * 4) * 72 + cc) = o;
    }
}

__device__ __forceinline__ void load_vb(const bf16* __restrict__ pkb, int jc,
                                        int q, int m, bf16x8 vb[8])
{
    #pragma unroll
    for (int nb = 0; nb < 8; ++nb)
        vb[nb] = *(const bf16x8*)(pkb + ((size_t)(((jc*8 + nb)*4 + q)*16 + m)) * 8);
}

__device__ __forceinline__ void substep(const bf16* mb, const float* skb,
    int buf, int st, int sub, int q, int m, float sq, const bf16x8 vb[8],
    float& lsum, f32x4 acc[8])
{
    bf16x8 mk = *(const bf16x8*)(mb + buf * 1152 + m * 72 + sub * 32 + q * 8);
    int jo = st * 64 + sub * 32 + q * 8;
    f32x4 s0 = *(const f32x4*)(skb + jo);
    f32x4 s1 = *(const f32x4*)(skb + jo + 4);
    float sks[8] = {s0[0], s0[1], s0[2], s0[3], s1[0], s1[1], s1[2], s1[3]};
    bf16x8 a;
    #pragma unroll
    for (int e = 0; e < 8; ++e) {
        float tv = sq + sks[e];
        float lr = fmaxf(tv, 0.01f * tv);
        float z  = lr * (float)mk[e];
        float p  = __expf(z);
        lsum += p;
        a[e] = (bf16)p;
    }
    #pragma unroll
    for (int nb = 0; nb < 8; ++nb)
        acc[nb] = MFMA16(a, vb[nb], acc[nb]);
}

__global__ __launch_bounds__(256) void k_att(
    const float* __restrict__ mask, const bf16* __restrict__ PK,
    const float* __restrict__ sqf, const float* __restrict__ skf,
    bf16* __restrict__ Oatt)
{
    __shared__ __align__(16) char smem[35840];
    int t    = threadIdx.x;
    int lane = t & 63, w = t >> 6;
    int b    = blockIdx.x & 7;                 // XCD locality: PK slice in L2
    int i0   = (blockIdx.x >> 3) << 4;
    int m = lane & 15, q = lane >> 4;

    bf16*  mbuf = (bf16*)(smem + w * 6912);            // 3 bufs x [16][72]
    float* skb  = (float*)(smem + 27648 + w * 2048);   // [512]

    {   // stage this wave's sk quarter
        const float* src = skf + b*CC + w*512;
        f32x4 v0 = *(const f32x4*)(src + lane*4);
        f32x4 v1 = *(const f32x4*)(src + 256 + lane*4);
        *(f32x4*)(skb + lane*4) = v0;
        *(f32x4*)(skb + 256 + lane*4) = v1;
    }
    float sq = sqf[b*CC + i0 + m];
    const float* mrow0 = mask + ((size_t)(b*CC + i0))*CC + w*512;
    const bf16*  pkb   = PK + (size_t)b * DD * CC;
    int jc0 = w * 16;

    f32x4 acc[8];
    #pragma unroll
    for (int nb = 0; nb < 8; ++nb) acc[nb] = {0.f, 0.f, 0.f, 0.f};
    float lsum = 0.f;

    {   MaskLd r0 = stage_load(mrow0, 0, lane);
        stage_write(r0, mbuf, 0, lane); }
    MaskLd r1 = stage_load(mrow0, 1, lane);
    MaskLd r2 = stage_load(mrow0, 2, lane);
    MaskLd r3;
    bf16x8 vbA[8], vbB[8];
    load_vb(pkb, jc0, q, m, vbA);

    int bm = 0;                                // st % 3
    for (int st = 0; st < 8; ++st) {
        if (st + 3 < 8) r3 = stage_load(mrow0, st + 3, lane);
        load_vb(pkb, jc0 + st*2 + 1, q, m, vbB);
        substep(mbuf, skb, bm, st, 0, q, m, sq, vbA, lsum, acc);
        if (st < 7) load_vb(pkb, jc0 + st*2 + 2, q, m, vbA);
        substep(mbuf, skb, bm, st, 1, q, m, sq, vbB, lsum, acc);
        int bw = bm + 1; if (bw == 3) bw = 0;
        if (st + 1 < 8) stage_write(r1, mbuf, bw, lane);
        r1 = r2; r2 = r3;
        bm = bw;
    }

    __syncthreads();            // mask/sk LDS dead for ALL waves
    float* Osh = (float*)smem;                // [4*16][132]
    float* Lsh = (float*)(smem + 33792);      // [64]
    lsum += __shfl_xor(lsum, 16, 64);
    lsum += __shfl_xor(lsum, 32, 64);
    if (q == 0) Lsh[w*16 + m] = lsum;
    #pragma unroll
    for (int nb = 0; nb < 8; ++nb)
        #pragma unroll
        for (int r = 0; r < 4; ++r)
            Osh[(w*16 + q*4 + r)*132 + nb*16 + m] = acc[nb][r];
    __syncthreads();

    int r  = t >> 4;
    int c0 = (t & 15) * 8;
    float l = Lsh[r] + Lsh[16 + r] + Lsh[32 + r] + Lsh[48 + r];
    float inv = 1.0f / l;
    bf16x8 o;
    #pragma unroll
    for (int e = 0; e < 8; ++e) {
        float s = Osh[r*132 + c0 + e] + Osh[(16 + r)*132 + c0 + e]
                + Osh[(32 + r)*132 + c0 + e] + Osh[(48 + r)*132 + c0 + e];
        o[e] = (bf16)(s * inv);
    }
    *(bf16x8*)(Oatt + ((size_t)(b*CC) + i0 + r)*DD + c0) = o;
}

// =====================================================================
// Kernel EPI: blocks 0..511: out[c] = ops[c]@G1 + ops[pred]@G2
//   + ops[succ]@G3 + O_att[c]@Wc + BBM  (32-row tiles).
// Blocks 512..519: edge rows 2046/2047 (2 edges per block).
// =====================================================================
__global__ __launch_bounds__(256) void k_epi(
    const bf16* __restrict__ ops16, const int* __restrict__ relations,
    const int* __restrict__ begins, const int* __restrict__ ends,
    const bf16* __restrict__ Oatt,
    const bf16* __restrict__ G1T, const bf16* __restrict__ G2T,
    const bf16* __restrict__ G3T, const bf16* __restrict__ WCT,
    const bf16* __restrict__ GBT, const bf16* __restrict__ GET,
    const float* __restrict__ BBM, const float* __restrict__ BBB,
    const float* __restrict__ BBE, float* __restrict__ out)
{
    __shared__ bf16 Abuf[32 * 136];
    __shared__ bf16 Bbuf[128 * 136];
    int t  = threadIdx.x;

    if (blockIdx.x >= 512) {
        // ---- edge path: 2 (b,which) per block ----
        __shared__ float meanv[2][128];
        int eidx  = (blockIdx.x - 512) * 2 + (t >> 7);
        int b     = eidx >> 1, which = eidx & 1;
        int tl    = t & 127;
        const int* idx = which ? (ends + b*JJN) : (begins + b*JJN);
        const bf16* opsb = ops16 + (size_t)b * CC * DD;
        float s = 0.f;
        for (int j = 0; j < JJN; ++j) {
            int rr = idx[j];
            s += (float)opsb[(size_t)rr*DD + tl];
        }
        meanv[t >> 7][tl] = s * (1.0f / (float)JJN);
        __syncthreads();
        const bf16* G   = which ? GET : GBT;
        const float* Bv = which ? BBE : BBB;
        const bf16* orow = Oatt + ((size_t)b*CC + (CC - 2 + which)) * DD;
        float a = Bv[tl];
        const bf16* gr = G + tl*128;
        const bf16* wr = WCT + tl*128;
        const float* mv = meanv[t >> 7];
        for (int d = 0; d < 128; ++d) {
            a += mv[d] * (float)gr[d];
            a += (float)orow[d] * (float)wr[d];
        }
        out[((size_t)b*CC + (CC - 2 + which))*DD + tl] = a;
        return;
    }

    int b  = blockIdx.x >> 6;
    int c0 = (blockIdx.x & 63) * 32;
    int lane = t & 63, w = t >> 6;
    int m = lane & 15, q = lane >> 4;

    f32x4 acc[2][2];
    #pragma unroll
    for (int rb = 0; rb < 2; ++rb)
        #pragma unroll
        for (int cb = 0; cb < 2; ++cb)
            acc[rb][cb] = {0.f, 0.f, 0.f, 0.f};

    const bf16* Bsrc[4] = {G1T, G2T, G3T, WCT};
    int arow = t >> 3, ao = (t & 7) * 16;
    int brow = t >> 1, bo = (t & 1) * 64;
    int c = c0 + arow;

    for (int term = 0; term < 4; ++term) {
        const bf16* src;
        if (term == 0)      src = ops16 + ((size_t)(b*CC + c)) * DD;
        else if (term == 3) src = Oatt  + ((size_t)(b*CC + c)) * DD;
        else {
            int ridx = relations[((size_t)b*(CC-2) + min(c, CC-3))*2 + (term - 1)];
            src = ops16 + ((size_t)(b*CC) + ridx) * DD;
        }
        *(uint4*)&Abuf[arow*136 + ao]     = *(const uint4*)(src + ao);
        *(uint4*)&Abuf[arow*136 + ao + 8] = *(const uint4*)(src + ao + 8);

        const uint4* bs = (const uint4*)(Bsrc[term] + brow*128 + bo);
        uint4* bd = (uint4*)&Bbuf[brow*136 + bo];
        #pragma unroll
        for (int ii = 0; ii < 8; ++ii) bd[ii] = bs[ii];
        __syncthreads();

        #pragma unroll
        for (int kc = 0; kc < 4; ++kc) {
            bf16x8 bfr[2];
            #pragma unroll
            for (int cb = 0; cb < 2; ++cb)
                bfr[cb] = *(const bf16x8*)&Bbuf[(w*32 + cb*16 + m)*136 + kc*32 + q*8];
            #pragma unroll
            for (int rb = 0; rb < 2; ++rb) {
                bf16x8 afr = *(const bf16x8*)&Abuf[(rb*16 + m)*136 + kc*32 + q*8];
                acc[rb][0] = MFMA16(afr, bfr[0], acc[rb][0]);
                acc[rb][1] = MFMA16(afr, bfr[1], acc[rb][1]);
            }
        }
        __syncthreads();
    }
    #pragma unroll
    for (int cb = 0; cb < 2; ++cb) {
        int col = w*32 + cb*16 + m;
        float bias = BBM[col];
        #pragma unroll
        for (int rb = 0; rb < 2; ++rb) {
            #pragma unroll
            for (int r = 0; r < 4; ++r) {
                int cg = c0 + rb*16 + q*4 + r;
                if (cg < CC - 2)
                    out[((size_t)(b*CC) + cg)*DD + col] = acc[rb][cb][r] + bias;
            }
        }
    }
}

// =====================================================================
extern "C" void kernel_launch(void* const* d_in, const int* in_sizes, int n_in,
                              void* d_out, int out_size, void* d_ws, size_t ws_size,
                              hipStream_t stream)
{
    const float* ops      = (const float*)d_in[0];
    const int*  relations = (const int*)d_in[1];
    const int*  begins    = (const int*)d_in[2];
    const int*  ends      = (const int*)d_in[3];
    const float* mask     = (const float*)d_in[4];
    const float* Wbegin   = (const float*)d_in[5];
    const float* bbegin   = (const float*)d_in[6];
    const float* Wend     = (const float*)d_in[7];
    const float* bend     = (const float*)d_in[8];
    const float* Wmix3    = (const float*)d_in[9];
    const float* bmix3    = (const float*)d_in[10];
    const float* Wqkv     = (const float*)d_in[11];
    const float* bqkv     = (const float*)d_in[12];
    const float* wscore   = (const float*)d_in[13];
    const float* bscore   = (const float*)d_in[14];
    const float* Wout     = (const float*)d_in[15];
    const float* bout     = (const float*)d_in[16];
    const float* Wmix2    = (const float*)d_in[17];
    const float* bmix2    = (const float*)d_in[18];
    float* outp = (float*)d_out;

    char* ws = (char*)d_ws;
    bf16*  PK    = (bf16*)(ws + WS_PK);
    bf16*  Oatt  = (bf16*)(ws + WS_OATT);
    bf16*  OPS16 = (bf16*)(ws + WS_OPS16);
    float* sqf   = (float*)(ws + WS_SQF);
    float* skf   = (float*)(ws + WS_SKF);
    bf16*  G1T   = (bf16*)(ws + WS_G1T);
    bf16*  G2T   = (bf16*)(ws + WS_G2T);
    bf16*  G3T   = (bf16*)(ws + WS_G3T);
    bf16*  WCT   = (bf16*)(ws + WS_WCT);
    bf16*  GBT   = (bf16*)(ws + WS_GBT);
    bf16*  GET   = (bf16*)(ws + WS_GET);
    bf16*  UQK   = (bf16*)(ws + WS_UQK);
    float* BBM   = (float*)(ws + WS_BBM);
    float* BBB   = (float*)(ws + WS_BBB);
    float* BBE   = (float*)(ws + WS_BBE);
    float* SC    = (float*)(ws + WS_SC);

    k_prepcast<<<dim3(1121), dim3(256), 0, stream>>>(
        ops, OPS16,
        Wmix3, Wmix2, Wout, Wbegin, Wend, Wqkv, bqkv, wscore, bscore,
        bmix3, bout, bmix2, bbegin, bend,
        G1T, G2T, G3T, WCT, GBT, GET, UQK, BBM, BBB, BBE, SC);

    k_v<<<dim3(128), dim3(256), 0, stream>>>(
        OPS16, Wqkv, bqkv, UQK, SC, PK, sqf, skf);

    k_att<<<dim3(1024), dim3(256), 0, stream>>>(
        mask, PK, sqf, skf, Oatt);

    k_epi<<<dim3(520), dim3(256), 0, stream>>>(
        OPS16, relations, begins, ends, Oatt,
        G1T, G2T, G3T, WCT, GBT, GET, BBM, BBB, BBE, outp);
}

// Round 7
// 295.068 us; speedup vs baseline: 1.1862x; 1.0038x over previous
//
#include <hip/hip_runtime.h>
#include <cstddef>

typedef __bf16 bf16;
typedef __bf16 bf16x4 __attribute__((ext_vector_type(4)));
typedef __bf16 bf16x8 __attribute__((ext_vector_type(8)));
typedef float  f32x4  __attribute__((ext_vector_type(4)));

#define MFMA16(a, b, c) __builtin_amdgcn_mfma_f32_16x16x32_bf16((a), (b), (c), 0, 0, 0)

// ---------------- constants ----------------
#define BB 8
#define CC 2048
#define DD 128
#define JJN 128

// ws layout (bytes)
#define WS_PK    ((size_t)0)          // bf16 [8][64jc][8nb][4q][16m][8e]
#define WS_OATT  ((size_t)4194304)    // bf16 [8][2048][128]
#define WS_OPS16 ((size_t)8388608)    // bf16 [8][2048][128]
#define WS_SQF   ((size_t)12582912)   // f32  [8][2048]
#define WS_SKF   ((size_t)12648448)   // f32  [8][2048]
#define WS_G1T   ((size_t)12713984)   // bf16 [128][128] (transposed: [e][d])
#define WS_G2T   ((size_t)12746752)
#define WS_G3T   ((size_t)12779520)
#define WS_WCT   ((size_t)12812288)
#define WS_GBT   ((size_t)12845056)
#define WS_GET   ((size_t)12877824)
#define WS_UQK   ((size_t)12910592)   // bf16 [2][128]
#define WS_BBM   ((size_t)12911104)   // f32 [128]
#define WS_BBB   ((size_t)12911616)   // f32 [128]
#define WS_BBE   ((size_t)12912128)   // f32 [128]
#define WS_SC    ((size_t)12912640)   // f32 [2]

// =====================================================================
// Kernel PREPCAST: blocks 0..1023 cast ops f32->bf16; 1024..1119 fold
// weight products; block 1120 vector folds.
// =====================================================================
__global__ __launch_bounds__(256) void k_prepcast(
    const float* __restrict__ ops, bf16* __restrict__ ops16,
    const float* __restrict__ Wmix3, const float* __restrict__ Wmix2,
    const float* __restrict__ Wout,  const float* __restrict__ Wbegin,
    const float* __restrict__ Wend,  const float* __restrict__ Wqkv,
    const float* __restrict__ bqkv,  const float* __restrict__ wscore,
    const float* __restrict__ bscore,const float* __restrict__ bmix3,
    const float* __restrict__ bout,  const float* __restrict__ bmix2,
    const float* __restrict__ bbegin,const float* __restrict__ bend,
    bf16* __restrict__ G1T, bf16* __restrict__ G2T, bf16* __restrict__ G3T,
    bf16* __restrict__ WCT, bf16* __restrict__ GBT, bf16* __restrict__ GET,
    bf16* __restrict__ uqk, float* __restrict__ BBM, float* __restrict__ BBB,
    float* __restrict__ BBE, float* __restrict__ sc)
{
    __shared__ bf16  LshT[128 * 132];
    __shared__ float Rsh[128 * 8];
    int wg = blockIdx.x;
    int t  = threadIdx.x;

    if (wg < 1024) {
        size_t i = (size_t)wg * 256 + t;
        f32x4 a = *(const f32x4*)(ops + i * 8);
        f32x4 b = *(const f32x4*)(ops + i * 8 + 4);
        bf16x8 o;
        #pragma unroll
        for (int e = 0; e < 4; ++e) { o[e] = (bf16)a[e]; o[4 + e] = (bf16)b[e]; }
        *(bf16x8*)(ops16 + i * 8) = o;
        return;
    }
    if (wg < 1120) {
        int id  = wg - 1024;
        int mat = id >> 4, sub = id & 15;
        const float* L; const float* R; bf16* O;
        switch (mat) {
            case 0: L = Wmix3;           R = Wmix2;           O = G1T; break;
            case 1: L = Wmix3 + 128*128; R = Wmix2;           O = G2T; break;
            case 2: L = Wmix3 + 256*128; R = Wmix2;           O = G3T; break;
            case 3: L = Wout;            R = Wmix2 + 128*128; O = WCT; break;
            case 4: L = Wbegin;          R = Wmix2;           O = GBT; break;
            default:L = Wend;            R = Wmix2;           O = GET; break;
        }
        int e0 = sub * 8;
        #pragma unroll
        for (int pass = 0; pass < 16; ++pass) {
            int idx = pass * 256 + t;
            int d   = idx >> 5;
            int f0  = (idx & 31) * 4;
            f32x4 v = *(const f32x4*)(L + d * 128 + f0);
            #pragma unroll
            for (int jj = 0; jj < 4; ++jj)
                LshT[(f0 + jj) * 132 + d] = (bf16)v[jj];
        }
        #pragma unroll
        for (int pass = 0; pass < 4; ++pass) {
            int idx = pass * 256 + t;
            int f   = idx >> 3;
            int ee  = idx & 7;
            Rsh[f * 8 + ee] = R[f * 128 + e0 + ee];
        }
        __syncthreads();
        int ee = t >> 5;
        int e  = e0 + ee;
        int d0 = (t & 31) * 4;
        float s[4] = {0.f, 0.f, 0.f, 0.f};
        for (int f = 0; f < 128; ++f) {
            bf16x4 lv = *(const bf16x4*)&LshT[f * 132 + d0];
            float rv = Rsh[f * 8 + ee];
            #pragma unroll
            for (int dd = 0; dd < 4; ++dd)
                s[dd] += (float)lv[dd] * rv;
        }
        #pragma unroll
        for (int dd = 0; dd < 4; ++dd)
            O[e * 128 + d0 + dd] = (bf16)s[dd];
        return;
    }
    if (t < 128) {
        int d = t;
        float su = 0.f, sk_ = 0.f;
        for (int e2 = 0; e2 < 128; ++e2) {
            su  += Wqkv[d*384 + e2]       * wscore[e2];
            sk_ += Wqkv[d*384 + 128 + e2] * wscore[128 + e2];
        }
        uqk[d]       = (bf16)su;
        uqk[128 + d] = (bf16)sk_;
        int e = d;
        float bm = 0.f, bon = 0.f, bb_ = 0.f, be_ = 0.f;
        for (int f = 0; f < 128; ++f) {
            float w2a = Wmix2[f*128 + e];
            float w2b = Wmix2[(128+f)*128 + e];
            bm  += bmix3[f]  * w2a;
            bon += bout[f]   * w2b;
            bb_ += bbegin[f] * w2a;
            be_ += bend[f]   * w2a;
        }
        float bm2 = bmix2[e];
        BBM[e] = bm  + bon + bm2;
        BBB[e] = bb_ + bon + bm2;
        BBE[e] = be_ + bon + bm2;
    } else if (t == 128) {
        float cq = 0.f, ck = 0.f;
        for (int e2 = 0; e2 < 128; ++e2) {
            cq += bqkv[e2]       * wscore[e2];
            ck += bqkv[128 + e2] * wscore[128 + e2];
        }
        sc[0] = cq + bscore[0];
        sc[1] = ck;
    }
}

// =====================================================================
// Kernel V: V = ops@Wv + b_v in PK layout. Epilogue scatters through
// LDS (reusing the A-tile region) and stores PK with contiguous dwordx4.
// =====================================================================
__global__ __launch_bounds__(256) void k_v(
    const bf16* __restrict__ ops16, const float* __restrict__ Wqkv,
    const float* __restrict__ bqkv, const bf16* __restrict__ uqk,
    const float* __restrict__ sc,
    bf16* __restrict__ PK, float* __restrict__ sqf, float* __restrict__ skf)
{
    __shared__ bf16 A[144 * 136];     // also reused as 32 KB pack buffer
    int b  = blockIdx.x >> 4;
    int jt = (blockIdx.x & 15) * 128;
    int t  = threadIdx.x;
    #pragma unroll
    for (int pass = 0; pass < 16; ++pass) {
        int idx = pass * 256 + t;
        int d   = idx >> 5;
        int n0  = (idx & 31) * 4;
        f32x4 v = *(const f32x4*)(Wqkv + d*384 + 256 + n0);
        #pragma unroll
        for (int jj = 0; jj < 4; ++jj)
            A[(n0 + jj)*136 + d] = (bf16)v[jj];
    }
    {
        int row = t >> 7, col = t & 127;
        A[(128 + row)*136 + col] = uqk[row*128 + col];
    }
    for (int idx = t; idx < 14*136; idx += 256)
        A[130*136 + idx] = (bf16)0.f;
    __syncthreads();

    int lane = t & 63, w = t >> 6;
    int m = lane & 15, q = lane >> 4;
    f32x4 acc[9][2];
    #pragma unroll
    for (int rb = 0; rb < 9; ++rb)
        #pragma unroll
        for (int cb = 0; cb < 2; ++cb)
            acc[rb][cb] = {0.f, 0.f, 0.f, 0.f};

    const bf16* opsb = ops16 + (size_t)b * CC * DD;
    #pragma unroll
    for (int kc = 0; kc < 4; ++kc) {
        bf16x8 bfr[2];
        #pragma unroll
        for (int cb = 0; cb < 2; ++cb) {
            int j = jt + w*32 + cb*16 + m;
            bfr[cb] = *(const bf16x8*)(opsb + (size_t)j*DD + kc*32 + q*8);
        }
        #pragma unroll
        for (int rb = 0; rb < 9; ++rb) {
            bf16x8 afr = *(const bf16x8*)&A[(rb*16 + m)*136 + kc*32 + q*8];
            acc[rb][0] = MFMA16(afr, bfr[0], acc[rb][0]);
            acc[rb][1] = MFMA16(afr, bfr[1], acc[rb][1]);
        }
    }
    float cqb = sc[0], ckv = sc[1];
    #pragma unroll
    for (int cb = 0; cb < 2; ++cb) {
        int j = jt + w*32 + cb*16 + m;
        if (q == 0) {
            sqf[b*CC + j] = acc[8][cb][0] + cqb;
            skf[b*CC + j] = acc[8][cb][1] + ckv;
        }
    }
    __syncthreads();               // all waves done reading A
    bf16* pack = A;                // 16384 elems = 32 KB
    #pragma unroll
    for (int cb = 0; cb < 2; ++cb) {
        int qq_base = cb*2 + (m>>3);
        int e       = m & 7;
        #pragma unroll
        for (int rb = 0; rb < 8; ++rb) {
            #pragma unroll
            for (int r = 0; r < 4; ++r) {
                float v = acc[rb][cb][r] + bqkv[256 + rb*16 + q*4 + r];
                pack[w*4096 + rb*512 + qq_base*128 + (q*4+r)*8 + e] = (bf16)v;
            }
        }
    }
    __syncthreads();
    bf16* pkb = PK + (size_t)b * DD * CC + (size_t)jt * 128;
    #pragma unroll
    for (int pass = 0; pass < 8; ++pass) {
        int lidx = pass * 256 + t;
        *(uint4*)(pkb + (size_t)lidx * 8) = *(const uint4*)&pack[lidx * 8];
    }
}

// =====================================================================
// Kernel ATT: streaming softmax-GEMM. Block = 32-row i-tile (two 16-row
// MFMA sub-tiles SHARING every PK B-fragment load -> PK L2 traffic
// halved). Wave w owns j-quarter (512 j = 8 steps of 64). Mask pipeline:
// depth-2 register buffer + double-buffered LDS stage (row stride 88
// bf16 for ~2-way banking).
// =====================================================================
struct MaskLd { f32x4 v[8]; };

__device__ __forceinline__ MaskLd stage_load(const float* __restrict__ mrow0,
                                             int st, int lane)
{
    MaskLd L;
    int rr0 = lane >> 4, cc = (lane & 15) * 4;
    const float* src = mrow0 + st * 64 + cc;
    #pragma unroll
    for (int k = 0; k < 8; ++k)
        L.v[k] = __builtin_nontemporal_load(
            (const f32x4*)(src + ((size_t)(rr0 + k * 4)) * CC));
    return L;
}

__device__ __forceinline__ void stage_write(const MaskLd& L, bf16* mb,
                                            int buf, int lane)
{
    int rr0 = lane >> 4, cc = (lane & 15) * 4;
    bf16* dst = mb + buf * 2816;                 // [32 rows][88]
    #pragma unroll
    for (int k = 0; k < 8; ++k) {
        bf16x4 o;
        #pragma unroll
        for (int e = 0; e < 4; ++e) o[e] = (bf16)L.v[k][e];
        *(bf16x4*)(dst + (rr0 + k * 4) * 88 + cc) = o;
    }
}

__device__ __forceinline__ void load_vb(const bf16* __restrict__ pkb, int jc,
                                        int q, int m, bf16x8 vb[8])
{
    #pragma unroll
    for (int nb = 0; nb < 8; ++nb)
        vb[nb] = *(const bf16x8*)(pkb + ((size_t)(((jc*8 + nb)*4 + q)*16 + m)) * 8);
}

__device__ __forceinline__ void substep(const bf16* mb, const float* skb,
    int buf, int st, int sub, int tile, int q, int m, float sq,
    const bf16x8 vb[8], float& lsum, f32x4 acc[8])
{
    bf16x8 mk = *(const bf16x8*)(mb + buf * 2816 + (tile*16 + m) * 88
                                 + sub * 32 + q * 8);
    int jo = st * 64 + sub * 32 + q * 8;
    f32x4 s0 = *(const f32x4*)(skb + jo);
    f32x4 s1 = *(const f32x4*)(skb + jo + 4);
    float sks[8] = {s0[0], s0[1], s0[2], s0[3], s1[0], s1[1], s1[2], s1[3]};
    bf16x8 a;
    #pragma unroll
    for (int e = 0; e < 8; ++e) {
        float tv = sq + sks[e];
        float lr = fmaxf(tv, 0.01f * tv);
        float z  = lr * (float)mk[e];
        float p  = __expf(z);
        lsum += p;
        a[e] = (bf16)p;
    }
    #pragma unroll
    for (int nb = 0; nb < 8; ++nb)
        acc[nb] = MFMA16(a, vb[nb], acc[nb]);
}

__global__ __launch_bounds__(256) void k_att(
    const float* __restrict__ mask, const bf16* __restrict__ PK,
    const float* __restrict__ sqf, const float* __restrict__ skf,
    bf16* __restrict__ Oatt)
{
    __shared__ __align__(16) char smem[53248];
    int t    = threadIdx.x;
    int lane = t & 63, w = t >> 6;
    int b    = blockIdx.x & 7;                 // XCD locality: PK slice in L2
    int i0   = (blockIdx.x >> 3) << 5;         // 64 i-tiles of 32 rows
    int m = lane & 15, q = lane >> 4;

    bf16*  mbuf = (bf16*)(smem + w * 11264);           // 2 bufs x [32][88]
    float* skb  = (float*)(smem + 45056 + w * 2048);   // [512]

    {   // stage this wave's sk quarter
        const float* src = skf + b*CC + w*512;
        f32x4 v0 = *(const f32x4*)(src + lane*4);
        f32x4 v1 = *(const f32x4*)(src + 256 + lane*4);
        *(f32x4*)(skb + lane*4) = v0;
        *(f32x4*)(skb + 256 + lane*4) = v1;
    }
    float sq0 = sqf[b*CC + i0 + m];
    float sq1 = sqf[b*CC + i0 + 16 + m];
    const float* mrow0 = mask + ((size_t)(b*CC + i0))*CC + w*512;
    const bf16*  pkb   = PK + (size_t)b * DD * CC;
    int jc0 = w * 16;

    f32x4 acc0[8], acc1[8];
    #pragma unroll
    for (int nb = 0; nb < 8; ++nb) {
        acc0[nb] = {0.f, 0.f, 0.f, 0.f};
        acc1[nb] = {0.f, 0.f, 0.f, 0.f};
    }
    float lsum0 = 0.f, lsum1 = 0.f;

    {   MaskLd r0 = stage_load(mrow0, 0, lane);
        stage_write(r0, mbuf, 0, lane); }
    MaskLd r1 = stage_load(mrow0, 1, lane);
    MaskLd r2 = stage_load(mrow0, 2, lane);

    int buf = 0;
    for (int st = 0; st < 8; ++st) {
        #pragma unroll
        for (int sub = 0; sub < 2; ++sub) {
            bf16x8 vb[8];
            load_vb(pkb, jc0 + st*2 + sub, q, m, vb);
            substep(mbuf, skb, buf, st, sub, 0, q, m, sq0, vb, lsum0, acc0);
            substep(mbuf, skb, buf, st, sub, 1, q, m, sq1, vb, lsum1, acc1);
        }
        if (st + 1 < 8) stage_write(r1, mbuf, buf ^ 1, lane);
        r1 = r2;
        if (st + 3 < 8) r2 = stage_load(mrow0, st + 3, lane);
        buf ^= 1;
    }

    __syncthreads();            // mask/sk LDS dead for ALL waves
    float* Osh = (float*)smem;                // [4*16][132]
    float* Lsh = (float*)(smem + 33792);      // [64]
    #pragma unroll
    for (int tile = 0; tile < 2; ++tile) {
        float ls = tile ? lsum1 : lsum0;
        ls += __shfl_xor(ls, 16, 64);
        ls += __shfl_xor(ls, 32, 64);
        if (q == 0) Lsh[w*16 + m] = ls;
        const f32x4* acc = tile ? acc1 : acc0;
        #pragma unroll
        for (int nb = 0; nb < 8; ++nb)
            #pragma unroll
            for (int r = 0; r < 4; ++r)
                Osh[(w*16 + q*4 + r)*132 + nb*16 + m] = acc[nb][r];
        __syncthreads();

        int r  = t >> 4;
        int c0 = (t & 15) * 8;
        float l = Lsh[r] + Lsh[16 + r] + Lsh[32 + r] + Lsh[48 + r];
        float inv = 1.0f / l;
        bf16x8 o;
        #pragma unroll
        for (int e = 0; e < 8; ++e) {
            float s = Osh[r*132 + c0 + e] + Osh[(16 + r)*132 + c0 + e]
                    + Osh[(32 + r)*132 + c0 + e] + Osh[(48 + r)*132 + c0 + e];
            o[e] = (bf16)(s * inv);
        }
        *(bf16x8*)(Oatt + ((size_t)(b*CC) + i0 + tile*16 + r)*DD + c0) = o;
        if (tile == 0) __syncthreads();
    }
}

// =====================================================================
// Kernel EPI: blocks 0..511: out[c] = ops[c]@G1 + ops[pred]@G2
//   + ops[succ]@G3 + O_att[c]@Wc + BBM  (32-row tiles).
// Blocks 512..519: edge rows 2046/2047 (2 edges per block).
// =====================================================================
__global__ __launch_bounds__(256) void k_epi(
    const bf16* __restrict__ ops16, const int* __restrict__ relations,
    const int* __restrict__ begins, const int* __restrict__ ends,
    const bf16* __restrict__ Oatt,
    const bf16* __restrict__ G1T, const bf16* __restrict__ G2T,
    const bf16* __restrict__ G3T, const bf16* __restrict__ WCT,
    const bf16* __restrict__ GBT, const bf16* __restrict__ GET,
    const float* __restrict__ BBM, const float* __restrict__ BBB,
    const float* __restrict__ BBE, float* __restrict__ out)
{
    __shared__ bf16 Abuf[32 * 136];
    __shared__ bf16 Bbuf[128 * 136];
    int t  = threadIdx.x;

    if (blockIdx.x >= 512) {
        // ---- edge path: 2 (b,which) per block ----
        __shared__ float meanv[2][128];
        int eidx  = (blockIdx.x - 512) * 2 + (t >> 7);
        int b     = eidx >> 1, which = eidx & 1;
        int tl    = t & 127;
        const int* idx = which ? (ends + b*JJN) : (begins + b*JJN);
        const bf16* opsb = ops16 + (size_t)b * CC * DD;
        float s = 0.f;
        for (int j = 0; j < JJN; ++j) {
            int rr = idx[j];
            s += (float)opsb[(size_t)rr*DD + tl];
        }
        meanv[t >> 7][tl] = s * (1.0f / (float)JJN);
        __syncthreads();
        const bf16* G   = which ? GET : GBT;
        const float* Bv = which ? BBE : BBB;
        const bf16* orow = Oatt + ((size_t)b*CC + (CC - 2 + which)) * DD;
        float a = Bv[tl];
        const bf16* gr = G + tl*128;
        const bf16* wr = WCT + tl*128;
        const float* mv = meanv[t >> 7];
        for (int d = 0; d < 128; ++d) {
            a += mv[d] * (float)gr[d];
            a += (float)orow[d] * (float)wr[d];
        }
        out[((size_t)b*CC + (CC - 2 + which))*DD + tl] = a;
        return;
    }

    int b  = blockIdx.x >> 6;
    int c0 = (blockIdx.x & 63) * 32;
    int lane = t & 63, w = t >> 6;
    int m = lane & 15, q = lane >> 4;

    f32x4 acc[2][2];
    #pragma unroll
    for (int rb = 0; rb < 2; ++rb)
        #pragma unroll
        for (int cb = 0; cb < 2; ++cb)
            acc[rb][cb] = {0.f, 0.f, 0.f, 0.f};

    const bf16* Bsrc[4] = {G1T, G2T, G3T, WCT};
    int arow = t >> 3, ao = (t & 7) * 16;
    int brow = t >> 1, bo = (t & 1) * 64;
    int c = c0 + arow;

    for (int term = 0; term < 4; ++term) {
        const bf16* src;
        if (term == 0)      src = ops16 + ((size_t)(b*CC + c)) * DD;
        else if (term == 3) src = Oatt  + ((size_t)(b*CC + c)) * DD;
        else {
            int ridx = relations[((size_t)b*(CC-2) + min(c, CC-3))*2 + (term - 1)];
            src = ops16 + ((size_t)(b*CC) + ridx) * DD;
        }
        *(uint4*)&Abuf[arow*136 + ao]     = *(const uint4*)(src + ao);
        *(uint4*)&Abuf[arow*136 + ao + 8] = *(const uint4*)(src + ao + 8);

        const uint4* bs = (const uint4*)(Bsrc[term] + brow*128 + bo);
        uint4* bd = (uint4*)&Bbuf[brow*136 + bo];
        #pragma unroll
        for (int ii = 0; ii < 8; ++ii) bd[ii] = bs[ii];
        __syncthreads();

        #pragma unroll
        for (int kc = 0; kc < 4; ++kc) {
            bf16x8 bfr[2];
            #pragma unroll
            for (int cb = 0; cb < 2; ++cb)
                bfr[cb] = *(const bf16x8*)&Bbuf[(w*32 + cb*16 + m)*136 + kc*32 + q*8];
            #pragma unroll
            for (int rb = 0; rb < 2; ++rb) {
                bf16x8 afr = *(const bf16x8*)&Abuf[(rb*16 + m)*136 + kc*32 + q*8];
                acc[rb][0] = MFMA16(afr, bfr[0], acc[rb][0]);
                acc[rb][1] = MFMA16(afr, bfr[1], acc[rb][1]);
            }
        }
        __syncthreads();
    }
    #pragma unroll
    for (int cb = 0; cb < 2; ++cb) {
        int col = w*32 + cb*16 + m;
        float bias = BBM[col];
        #pragma unroll
        for (int rb = 0; rb < 2; ++rb) {
            #pragma unroll
            for (int r = 0; r < 4; ++r) {
                int cg = c0 + rb*16 + q*4 + r;
                if (cg < CC - 2)
                    out[((size_t)(b*CC) + cg)*DD + col] = acc[rb][cb][r] + bias;
            }
        }
    }
}

// =====================================================================
extern "C" void kernel_launch(void* const* d_in, const int* in_sizes, int n_in,
                              void* d_out, int out_size, void* d_ws, size_t ws_size,
                              hipStream_t stream)
{
    const float* ops      = (const float*)d_in[0];
    const int*  relations = (const int*)d_in[1];
    const int*  begins    = (const int*)d_in[2];
    const int*  ends      = (const int*)d_in[3];
    const float* mask     = (const float*)d_in[4];
    const float* Wbegin   = (const float*)d_in[5];
    const float* bbegin   = (const float*)d_in[6];
    const float* Wend     = (const float*)d_in[7];
    const float* bend     = (const float*)d_in[8];
    const float* Wmix3    = (const float*)d_in[9];
    const float* bmix3    = (const float*)d_in[10];
    const float* Wqkv     = (const float*)d_in[11];
    const float* bqkv     = (const float*)d_in[12];
    const float* wscore   = (const float*)d_in[13];
    const float* bscore   = (const float*)d_in[14];
    const float* Wout     = (const float*)d_in[15];
    const float* bout     = (const float*)d_in[16];
    const float* Wmix2    = (const float*)d_in[17];
    const float* bmix2    = (const float*)d_in[18];
    float* outp = (float*)d_out;

    char* ws = (char*)d_ws;
    bf16*  PK    = (bf16*)(ws + WS_PK);
    bf16*  Oatt  = (bf16*)(ws + WS_OATT);
    bf16*  OPS16 = (bf16*)(ws + WS_OPS16);
    float* sqf   = (float*)(ws + WS_SQF);
    float* skf   = (float*)(ws + WS_SKF);
    bf16*  G1T   = (bf16*)(ws + WS_G1T);
    bf16*  G2T   = (bf16*)(ws + WS_G2T);
    bf16*  G3T   = (bf16*)(ws + WS_G3T);
    bf16*  WCT   = (bf16*)(ws + WS_WCT);
    bf16*  GBT   = (bf16*)(ws + WS_GBT);
    bf16*  GET   = (bf16*)(ws + WS_GET);
    bf16*  UQK   = (bf16*)(ws + WS_UQK);
    float* BBM   = (float*)(ws + WS_BBM);
    float* BBB   = (float*)(ws + WS_BBB);
    float* BBE   = (float*)(ws + WS_BBE);
    float* SC    = (float*)(ws + WS_SC);

    k_prepcast<<<dim3(1121), dim3(256), 0, stream>>>(
        ops, OPS16,
        Wmix3, Wmix2, Wout, Wbegin, Wend, Wqkv, bqkv, wscore, bscore,
        bmix3, bout, bmix2, bbegin, bend,
        G1T, G2T, G3T, WCT, GBT, GET, UQK, BBM, BBB, BBE, SC);

    k_v<<<dim3(128), dim3(256), 0, stream>>>(
        OPS16, Wqkv, bqkv, UQK, SC, PK, sqf, skf);

    k_att<<<dim3(512), dim3(256), 0, stream>>>(
        mask, PK, sqf, skf, Oatt);

    k_epi<<<dim3(520), dim3(256), 0, stream>>>(
        OPS16, relations, begins, ends, Oatt,
        G1T, G2T, G3T, WCT, GBT, GET, BBM, BBB, BBE, outp);
}

// Round 8
// 287.246 us; speedup vs baseline: 1.2185x; 1.0272x over previous
//
#include <hip/hip_runtime.h>
#include <cstddef>

typedef __bf16 bf16;
typedef __bf16 bf16x4 __attribute__((ext_vector_type(4)));
typedef __bf16 bf16x8 __attribute__((ext_vector_type(8)));
typedef float  f32x4  __attribute__((ext_vector_type(4)));

#define MFMA16(a, b, c) __builtin_amdgcn_mfma_f32_16x16x32_bf16((a), (b), (c), 0, 0, 0)

// ---------------- constants ----------------
#define BB 8
#define CC 2048
#define DD 128
#define JJN 128

// ws layout (bytes)
#define WS_PK    ((size_t)0)          // bf16 [8][64jc][8nb][4q][16m][8e]
#define WS_OATT  ((size_t)4194304)    // bf16 [8][2048][128]
#define WS_OPS16 ((size_t)8388608)    // bf16 [8][2048][128]
#define WS_SQF   ((size_t)12582912)   // f32  [8][2048]
#define WS_SKF   ((size_t)12648448)   // f32  [8][2048]
#define WS_G1T   ((size_t)12713984)   // bf16 [128][128] (transposed: [e][d])
#define WS_G2T   ((size_t)12746752)
#define WS_G3T   ((size_t)12779520)
#define WS_WCT   ((size_t)12812288)
#define WS_GBT   ((size_t)12845056)
#define WS_GET   ((size_t)12877824)
#define WS_UQK   ((size_t)12910592)   // bf16 [2][128]
#define WS_BBM   ((size_t)12911104)   // f32 [128]
#define WS_BBB   ((size_t)12911616)   // f32 [128]
#define WS_BBE   ((size_t)12912128)   // f32 [128]
#define WS_SC    ((size_t)12912640)   // f32 [2]
#define WS_WCN   ((size_t)12913152)   // bf16 [128][128] non-transposed [d][e]
#define WS_GBN   ((size_t)12945920)
#define WS_GEN   ((size_t)12978688)

// =====================================================================
// Kernel PREPCAST: block 0 = vector folds (coalesced, starts first);
// blocks 1..96 = weight-product folds; 97..1120 = ops cast f32->bf16.
// =====================================================================
__global__ __launch_bounds__(256) void k_prepcast(
    const float* __restrict__ ops, bf16* __restrict__ ops16,
    const float* __restrict__ Wmix3, const float* __restrict__ Wmix2,
    const float* __restrict__ Wout,  const float* __restrict__ Wbegin,
    const float* __restrict__ Wend,  const float* __restrict__ Wqkv,
    const float* __restrict__ bqkv,  const float* __restrict__ wscore,
    const float* __restrict__ bscore,const float* __restrict__ bmix3,
    const float* __restrict__ bout,  const float* __restrict__ bmix2,
    const float* __restrict__ bbegin,const float* __restrict__ bend,
    bf16* __restrict__ G1T, bf16* __restrict__ G2T, bf16* __restrict__ G3T,
    bf16* __restrict__ WCT, bf16* __restrict__ GBT, bf16* __restrict__ GET,
    bf16* __restrict__ WCN, bf16* __restrict__ GBN, bf16* __restrict__ GEN,
    bf16* __restrict__ uqk, float* __restrict__ BBM, float* __restrict__ BBB,
    float* __restrict__ BBE, float* __restrict__ sc)
{
    __shared__ bf16  LshT[128 * 132];
    __shared__ float Rsh[128 * 8];
    int wg = blockIdx.x;
    int t  = threadIdx.x;

    if (wg == 0) {
        // ===== vector folds, fully coalesced via LDS staging =====
        // Phase 1: uq/uk  (uq[d] = sum_e Wqkv[d][e]*ws[e], half 0;
        //                  uk[d] = sum_e Wqkv[d][128+e]*ws[128+e], half 1)
        for (int half = 0; half < 2; ++half) {
            #pragma unroll
            for (int pass = 0; pass < 16; ++pass) {       // stage [e][d]
                int idx = pass * 256 + t;
                int d   = idx >> 5;
                int e0  = (idx & 31) * 4;
                f32x4 v = *(const f32x4*)(Wqkv + d*384 + half*128 + e0);
                #pragma unroll
                for (int jj = 0; jj < 4; ++jj)
                    LshT[(e0 + jj)*132 + d] = (bf16)v[jj];
            }
            if (t < 32) {
                f32x4 wv = *(const f32x4*)(wscore + half*128 + t*4);
                #pragma unroll
                for (int jj = 0; jj < 4; ++jj) Rsh[t*4 + jj] = wv[jj];
            }
            __syncthreads();
            if (t < 128) {
                float s = 0.f;
                for (int e = 0; e < 128; ++e)
                    s += (float)LshT[e*132 + t] * Rsh[e];
                uqk[half*128 + t] = (bf16)s;
            }
            __syncthreads();
        }
        // Phase 2: BBM/BBB/BBE components.
        //   half 0: rows 0..127 of Wmix2 (w2a) with bmix3/bbegin/bend
        //   half 1: rows 128..255 (w2b) with bout
        float bm = 0.f, bb_ = 0.f, be_ = 0.f, bon = 0.f;
        for (int half = 0; half < 2; ++half) {
            #pragma unroll
            for (int pass = 0; pass < 16; ++pass) {       // stage [f][e]
                int idx = pass * 256 + t;
                int f   = idx >> 5;
                int e0  = (idx & 31) * 4;
                f32x4 v = *(const f32x4*)(Wmix2 + (size_t)(half*128 + f)*128 + e0);
                #pragma unroll
                for (int jj = 0; jj < 4; ++jj)
                    LshT[f*132 + e0 + jj] = (bf16)v[jj];
            }
            if (t < 32) {
                if (half == 0) {
                    f32x4 v0 = *(const f32x4*)(bmix3  + t*4);
                    f32x4 v1 = *(const f32x4*)(bbegin + t*4);
                    f32x4 v2 = *(const f32x4*)(bend   + t*4);
                    #pragma unroll
                    for (int jj = 0; jj < 4; ++jj) {
                        Rsh[t*4 + jj]       = v0[jj];
                        Rsh[128 + t*4 + jj] = v1[jj];
                        Rsh[256 + t*4 + jj] = v2[jj];
                    }
                } else {
                    f32x4 v3 = *(const f32x4*)(bout + t*4);
                    #pragma unroll
                    for (int jj = 0; jj < 4; ++jj) Rsh[t*4 + jj] = v3[jj];
                }
            }
            __syncthreads();
            if (t < 128) {
                if (half == 0) {
                    for (int f = 0; f < 128; ++f) {
                        float wv = (float)LshT[f*132 + t];
                        bm  += Rsh[f]       * wv;
                        bb_ += Rsh[128 + f] * wv;
                        be_ += Rsh[256 + f] * wv;
                    }
                } else {
                    for (int f = 0; f < 128; ++f)
                        bon += Rsh[f] * (float)LshT[f*132 + t];
                }
            }
            __syncthreads();
        }
        if (t < 128) {
            float bm2 = bmix2[t];
            BBM[t] = bm  + bon + bm2;
            BBB[t] = bb_ + bon + bm2;
            BBE[t] = be_ + bon + bm2;
        }
        // Phase 3: sc (parallel partials + tiny serial sum)
        if (t >= 128) {
            int e2 = t - 128;
            Rsh[512 + e2] = bqkv[e2]       * wscore[e2];
            Rsh[640 + e2] = bqkv[128 + e2] * wscore[128 + e2];
        }
        __syncthreads();
        if (t == 0) {
            float cq = 0.f, ck = 0.f;
            for (int e2 = 0; e2 < 128; ++e2) {
                cq += Rsh[512 + e2];
                ck += Rsh[640 + e2];
            }
            sc[0] = cq + bscore[0];
            sc[1] = ck;
        }
        return;
    }
    if (wg <= 96) {
        int id  = wg - 1;
        int mat = id >> 4, sub = id & 15;
        const float* L; const float* R; bf16* O; bf16* O2;
        switch (mat) {
            case 0: L = Wmix3;           R = Wmix2;           O = G1T; O2 = nullptr; break;
            case 1: L = Wmix3 + 128*128; R = Wmix2;           O = G2T; O2 = nullptr; break;
            case 2: L = Wmix3 + 256*128; R = Wmix2;           O = G3T; O2 = nullptr; break;
            case 3: L = Wout;            R = Wmix2 + 128*128; O = WCT; O2 = WCN; break;
            case 4: L = Wbegin;          R = Wmix2;           O = GBT; O2 = GBN; break;
            default:L = Wend;            R = Wmix2;           O = GET; O2 = GEN; break;
        }
        int e0 = sub * 8;
        #pragma unroll
        for (int pass = 0; pass < 16; ++pass) {
            int idx = pass * 256 + t;
            int d   = idx >> 5;
            int f0  = (idx & 31) * 4;
            f32x4 v = *(const f32x4*)(L + d * 128 + f0);
            #pragma unroll
            for (int jj = 0; jj < 4; ++jj)
                LshT[(f0 + jj) * 132 + d] = (bf16)v[jj];
        }
        #pragma unroll
        for (int pass = 0; pass < 4; ++pass) {
            int idx = pass * 256 + t;
            int f   = idx >> 3;
            int ee  = idx & 7;
            Rsh[f * 8 + ee] = R[f * 128 + e0 + ee];
        }
        __syncthreads();
        int ee = t >> 5;
        int e  = e0 + ee;
        int d0 = (t & 31) * 4;
        float s[4] = {0.f, 0.f, 0.f, 0.f};
        for (int f = 0; f < 128; ++f) {
            bf16x4 lv = *(const bf16x4*)&LshT[f * 132 + d0];
            float rv = Rsh[f * 8 + ee];
            #pragma unroll
            for (int dd = 0; dd < 4; ++dd)
                s[dd] += (float)lv[dd] * rv;
        }
        #pragma unroll
        for (int dd = 0; dd < 4; ++dd) {
            O[e * 128 + d0 + dd] = (bf16)s[dd];
            if (O2) O2[(d0 + dd) * 128 + e] = (bf16)s[dd];
        }
        return;
    }
    // ---- cast ----
    size_t i = (size_t)(wg - 97) * 256 + t;
    f32x4 a = *(const f32x4*)(ops + i * 8);
    f32x4 b = *(const f32x4*)(ops + i * 8 + 4);
    bf16x8 o;
    #pragma unroll
    for (int e = 0; e < 4; ++e) { o[e] = (bf16)a[e]; o[4 + e] = (bf16)b[e]; }
    *(bf16x8*)(ops16 + i * 8) = o;
}

// =====================================================================
// Kernel V: V = ops@Wv + b_v in PK layout. Epilogue scatters through
// LDS (reusing the A-tile region) and stores PK with contiguous dwordx4.
// =====================================================================
__global__ __launch_bounds__(256) void k_v(
    const bf16* __restrict__ ops16, const float* __restrict__ Wqkv,
    const float* __restrict__ bqkv, const bf16* __restrict__ uqk,
    const float* __restrict__ sc,
    bf16* __restrict__ PK, float* __restrict__ sqf, float* __restrict__ skf)
{
    __shared__ bf16 A[144 * 136];     // also reused as 32 KB pack buffer
    int b  = blockIdx.x >> 4;
    int jt = (blockIdx.x & 15) * 128;
    int t  = threadIdx.x;
    #pragma unroll
    for (int pass = 0; pass < 16; ++pass) {
        int idx = pass * 256 + t;
        int d   = idx >> 5;
        int n0  = (idx & 31) * 4;
        f32x4 v = *(const f32x4*)(Wqkv + d*384 + 256 + n0);
        #pragma unroll
        for (int jj = 0; jj < 4; ++jj)
            A[(n0 + jj)*136 + d] = (bf16)v[jj];
    }
    {
        int row = t >> 7, col = t & 127;
        A[(128 + row)*136 + col] = uqk[row*128 + col];
    }
    for (int idx = t; idx < 14*136; idx += 256)
        A[130*136 + idx] = (bf16)0.f;
    __syncthreads();

    int lane = t & 63, w = t >> 6;
    int m = lane & 15, q = lane >> 4;
    f32x4 acc[9][2];
    #pragma unroll
    for (int rb = 0; rb < 9; ++rb)
        #pragma unroll
        for (int cb = 0; cb < 2; ++cb)
            acc[rb][cb] = {0.f, 0.f, 0.f, 0.f};

    const bf16* opsb = ops16 + (size_t)b * CC * DD;
    #pragma unroll
    for (int kc = 0; kc < 4; ++kc) {
        bf16x8 bfr[2];
        #pragma unroll
        for (int cb = 0; cb < 2; ++cb) {
            int j = jt + w*32 + cb*16 + m;
            bfr[cb] = *(const bf16x8*)(opsb + (size_t)j*DD + kc*32 + q*8);
        }
        #pragma unroll
        for (int rb = 0; rb < 9; ++rb) {
            bf16x8 afr = *(const bf16x8*)&A[(rb*16 + m)*136 + kc*32 + q*8];
            acc[rb][0] = MFMA16(afr, bfr[0], acc[rb][0]);
            acc[rb][1] = MFMA16(afr, bfr[1], acc[rb][1]);
        }
    }
    float cqb = sc[0], ckv = sc[1];
    #pragma unroll
    for (int cb = 0; cb < 2; ++cb) {
        int j = jt + w*32 + cb*16 + m;
        if (q == 0) {
            sqf[b*CC + j] = acc[8][cb][0] + cqb;
            skf[b*CC + j] = acc[8][cb][1] + ckv;
        }
    }
    __syncthreads();               // all waves done reading A
    bf16* pack = A;                // 16384 elems = 32 KB
    #pragma unroll
    for (int cb = 0; cb < 2; ++cb) {
        int qq_base = cb*2 + (m>>3);
        int e       = m & 7;
        #pragma unroll
        for (int rb = 0; rb < 8; ++rb) {
            #pragma unroll
            for (int r = 0; r < 4; ++r) {
                float v = acc[rb][cb][r] + bqkv[256 + rb*16 + q*4 + r];
                pack[w*4096 + rb*512 + qq_base*128 + (q*4+r)*8 + e] = (bf16)v;
            }
        }
    }
    __syncthreads();
    bf16* pkb = PK + (size_t)b * DD * CC + (size_t)jt * 128;
    #pragma unroll
    for (int pass = 0; pass < 8; ++pass) {
        int lidx = pass * 256 + t;
        *(uint4*)(pkb + (size_t)lidx * 8) = *(const uint4*)&pack[lidx * 8];
    }
}

// =====================================================================
// Kernel ATT: streaming softmax-GEMM (unchanged from round 7).
// =====================================================================
struct MaskLd { f32x4 v[8]; };

__device__ __forceinline__ MaskLd stage_load(const float* __restrict__ mrow0,
                                             int st, int lane)
{
    MaskLd L;
    int rr0 = lane >> 4, cc = (lane & 15) * 4;
    const float* src = mrow0 + st * 64 + cc;
    #pragma unroll
    for (int k = 0; k < 8; ++k)
        L.v[k] = __builtin_nontemporal_load(
            (const f32x4*)(src + ((size_t)(rr0 + k * 4)) * CC));
    return L;
}

__device__ __forceinline__ void stage_write(const MaskLd& L, bf16* mb,
                                            int buf, int lane)
{
    int rr0 = lane >> 4, cc = (lane & 15) * 4;
    bf16* dst = mb + buf * 2816;                 // [32 rows][88]
    #pragma unroll
    for (int k = 0; k < 8; ++k) {
        bf16x4 o;
        #pragma unroll
        for (int e = 0; e < 4; ++e) o[e] = (bf16)L.v[k][e];
        *(bf16x4*)(dst + (rr0 + k * 4) * 88 + cc) = o;
    }
}

__device__ __forceinline__ void load_vb(const bf16* __restrict__ pkb, int jc,
                                        int q, int m, bf16x8 vb[8])
{
    #pragma unroll
    for (int nb = 0; nb < 8; ++nb)
        vb[nb] = *(const bf16x8*)(pkb + ((size_t)(((jc*8 + nb)*4 + q)*16 + m)) * 8);
}

__device__ __forceinline__ void substep(const bf16* mb, const float* skb,
    int buf, int st, int sub, int tile, int q, int m, float sq,
    const bf16x8 vb[8], float& lsum, f32x4 acc[8])
{
    bf16x8 mk = *(const bf16x8*)(mb + buf * 2816 + (tile*16 + m) * 88
                                 + sub * 32 + q * 8);
    int jo = st * 64 + sub * 32 + q * 8;
    f32x4 s0 = *(const f32x4*)(skb + jo);
    f32x4 s1 = *(const f32x4*)(skb + jo + 4);
    float sks[8] = {s0[0], s0[1], s0[2], s0[3], s1[0], s1[1], s1[2], s1[3]};
    bf16x8 a;
    #pragma unroll
    for (int e = 0; e < 8; ++e) {
        float tv = sq + sks[e];
        float lr = fmaxf(tv, 0.01f * tv);
        float z  = lr * (float)mk[e];
        float p  = __expf(z);
        lsum += p;
        a[e] = (bf16)p;
    }
    #pragma unroll
    for (int nb = 0; nb < 8; ++nb)
        acc[nb] = MFMA16(a, vb[nb], acc[nb]);
}

__global__ __launch_bounds__(256) void k_att(
    const float* __restrict__ mask, const bf16* __restrict__ PK,
    const float* __restrict__ sqf, const float* __restrict__ skf,
    bf16* __restrict__ Oatt)
{
    __shared__ __align__(16) char smem[53248];
    int t    = threadIdx.x;
    int lane = t & 63, w = t >> 6;
    int b    = blockIdx.x & 7;
    int i0   = (blockIdx.x >> 3) << 5;
    int m = lane & 15, q = lane >> 4;

    bf16*  mbuf = (bf16*)(smem + w * 11264);           // 2 bufs x [32][88]
    float* skb  = (float*)(smem + 45056 + w * 2048);   // [512]

    {
        const float* src = skf + b*CC + w*512;
        f32x4 v0 = *(const f32x4*)(src + lane*4);
        f32x4 v1 = *(const f32x4*)(src + 256 + lane*4);
        *(f32x4*)(skb + lane*4) = v0;
        *(f32x4*)(skb + 256 + lane*4) = v1;
    }
    float sq0 = sqf[b*CC + i0 + m];
    float sq1 = sqf[b*CC + i0 + 16 + m];
    const float* mrow0 = mask + ((size_t)(b*CC + i0))*CC + w*512;
    const bf16*  pkb   = PK + (size_t)b * DD * CC;
    int jc0 = w * 16;

    f32x4 acc0[8], acc1[8];
    #pragma unroll
    for (int nb = 0; nb < 8; ++nb) {
        acc0[nb] = {0.f, 0.f, 0.f, 0.f};
        acc1[nb] = {0.f, 0.f, 0.f, 0.f};
    }
    float lsum0 = 0.f, lsum1 = 0.f;

    {   MaskLd r0 = stage_load(mrow0, 0, lane);
        stage_write(r0, mbuf, 0, lane); }
    MaskLd r1 = stage_load(mrow0, 1, lane);
    MaskLd r2 = stage_load(mrow0, 2, lane);

    int buf = 0;
    for (int st = 0; st < 8; ++st) {
        #pragma unroll
        for (int sub = 0; sub < 2; ++sub) {
            bf16x8 vb[8];
            load_vb(pkb, jc0 + st*2 + sub, q, m, vb);
            substep(mbuf, skb, buf, st, sub, 0, q, m, sq0, vb, lsum0, acc0);
            substep(mbuf, skb, buf, st, sub, 1, q, m, sq1, vb, lsum1, acc1);
        }
        if (st + 1 < 8) stage_write(r1, mbuf, buf ^ 1, lane);
        r1 = r2;
        if (st + 3 < 8) r2 = stage_load(mrow0, st + 3, lane);
        buf ^= 1;
    }

    __syncthreads();
    float* Osh = (float*)smem;                // [4*16][132]
    float* Lsh = (float*)(smem + 33792);      // [64]
    #pragma unroll
    for (int tile = 0; tile < 2; ++tile) {
        float ls = tile ? lsum1 : lsum0;
        ls += __shfl_xor(ls, 16, 64);
        ls += __shfl_xor(ls, 32, 64);
        if (q == 0) Lsh[w*16 + m] = ls;
        const f32x4* acc = tile ? acc1 : acc0;
        #pragma unroll
        for (int nb = 0; nb < 8; ++nb)
            #pragma unroll
            for (int r = 0; r < 4; ++r)
                Osh[(w*16 + q*4 + r)*132 + nb*16 + m] = acc[nb][r];
        __syncthreads();

        int r  = t >> 4;
        int c0 = (t & 15) * 8;
        float l = Lsh[r] + Lsh[16 + r] + Lsh[32 + r] + Lsh[48 + r];
        float inv = 1.0f / l;
        bf16x8 o;
        #pragma unroll
        for (int e = 0; e < 8; ++e) {
            float s = Osh[r*132 + c0 + e] + Osh[(16 + r)*132 + c0 + e]
                    + Osh[(32 + r)*132 + c0 + e] + Osh[(48 + r)*132 + c0 + e];
            o[e] = (bf16)(s * inv);
        }
        *(bf16x8*)(Oatt + ((size_t)(b*CC) + i0 + tile*16 + r)*DD + c0) = o;
        if (tile == 0) __syncthreads();
    }
}

// =====================================================================
// Kernel EPI: blocks 0..7 = edge rows 2046/2047 (launched FIRST, with
// lane-contiguous non-transposed folded weights); blocks 8..519 = main
// 32-row GEMM tiles.
// =====================================================================
__global__ __launch_bounds__(256) void k_epi(
    const bf16* __restrict__ ops16, const int* __restrict__ relations,
    const int* __restrict__ begins, const int* __restrict__ ends,
    const bf16* __restrict__ Oatt,
    const bf16* __restrict__ G1T, const bf16* __restrict__ G2T,
    const bf16* __restrict__ G3T, const bf16* __restrict__ WCT,
    const bf16* __restrict__ GBN, const bf16* __restrict__ GEN,
    const bf16* __restrict__ WCN,
    const float* __restrict__ BBM, const float* __restrict__ BBB,
    const float* __restrict__ BBE, float* __restrict__ out)
{
    __shared__ bf16 Abuf[32 * 136];
    __shared__ bf16 Bbuf[128 * 136];
    int t  = threadIdx.x;

    if (blockIdx.x < 8) {
        // ---- edge path: 2 (b,which) tasks per block ----
        __shared__ float meanv[2][128];
        int eidx  = blockIdx.x * 2 + (t >> 7);
        int b     = eidx >> 1, which = eidx & 1;
        int tl    = t & 127;
        const int* idx = which ? (ends + b*JJN) : (begins + b*JJN);
        const bf16* opsb = ops16 + (size_t)b * CC * DD;
        float s0 = 0.f, s1 = 0.f;
        for (int j = 0; j < JJN; j += 2) {
            int r0 = idx[j], r1 = idx[j+1];
            s0 += (float)opsb[(size_t)r0*DD + tl];
            s1 += (float)opsb[(size_t)r1*DD + tl];
        }
        meanv[t >> 7][tl] = (s0 + s1) * (1.0f / (float)JJN);
        __syncthreads();
        const bf16* G   = which ? GEN : GBN;
        const float* Bv = which ? BBE : BBB;
        const bf16* orow = Oatt + ((size_t)b*CC + (CC - 2 + which)) * DD;
        float a = Bv[tl];
        const float* mv = meanv[t >> 7];
        for (int d = 0; d < 128; ++d) {
            a += mv[d] * (float)G[d*128 + tl];          // lane-contiguous
            a += (float)orow[d] * (float)WCN[d*128 + tl];
        }
        out[((size_t)b*CC + (CC - 2 + which))*DD + tl] = a;
        return;
    }

    int gid = blockIdx.x - 8;
    int b  = gid >> 6;
    int c0 = (gid & 63) * 32;
    int lane = t & 63, w = t >> 6;
    int m = lane & 15, q = lane >> 4;

    f32x4 acc[2][2];
    #pragma unroll
    for (int rb = 0; rb < 2; ++rb)
        #pragma unroll
        for (int cb = 0; cb < 2; ++cb)
            acc[rb][cb] = {0.f, 0.f, 0.f, 0.f};

    const bf16* Bsrc[4] = {G1T, G2T, G3T, WCT};
    int arow = t >> 3, ao = (t & 7) * 16;
    int brow = t >> 1, bo = (t & 1) * 64;
    int c = c0 + arow;

    for (int term = 0; term < 4; ++term) {
        const bf16* src;
        if (term == 0)      src = ops16 + ((size_t)(b*CC + c)) * DD;
        else if (term == 3) src = Oatt  + ((size_t)(b*CC + c)) * DD;
        else {
            int ridx = relations[((size_t)b*(CC-2) + min(c, CC-3))*2 + (term - 1)];
            src = ops16 + ((size_t)(b*CC) + ridx) * DD;
        }
        *(uint4*)&Abuf[arow*136 + ao]     = *(const uint4*)(src + ao);
        *(uint4*)&Abuf[arow*136 + ao + 8] = *(const uint4*)(src + ao + 8);

        const uint4* bs = (const uint4*)(Bsrc[term] + brow*128 + bo);
        uint4* bd = (uint4*)&Bbuf[brow*136 + bo];
        #pragma unroll
        for (int ii = 0; ii < 8; ++ii) bd[ii] = bs[ii];
        __syncthreads();

        #pragma unroll
        for (int kc = 0; kc < 4; ++kc) {
            bf16x8 bfr[2];
            #pragma unroll
            for (int cb = 0; cb < 2; ++cb)
                bfr[cb] = *(const bf16x8*)&Bbuf[(w*32 + cb*16 + m)*136 + kc*32 + q*8];
            #pragma unroll
            for (int rb = 0; rb < 2; ++rb) {
                bf16x8 afr = *(const bf16x8*)&Abuf[(rb*16 + m)*136 + kc*32 + q*8];
                acc[rb][0] = MFMA16(afr, bfr[0], acc[rb][0]);
                acc[rb][1] = MFMA16(afr, bfr[1], acc[rb][1]);
            }
        }
        __syncthreads();
    }
    #pragma unroll
    for (int cb = 0; cb < 2; ++cb) {
        int col = w*32 + cb*16 + m;
        float bias = BBM[col];
        #pragma unroll
        for (int rb = 0; rb < 2; ++rb) {
            #pragma unroll
            for (int r = 0; r < 4; ++r) {
                int cg = c0 + rb*16 + q*4 + r;
                if (cg < CC - 2)
                    out[((size_t)(b*CC) + cg)*DD + col] = acc[rb][cb][r] + bias;
            }
        }
    }
}

// =====================================================================
extern "C" void kernel_launch(void* const* d_in, const int* in_sizes, int n_in,
                              void* d_out, int out_size, void* d_ws, size_t ws_size,
                              hipStream_t stream)
{
    const float* ops      = (const float*)d_in[0];
    const int*  relations = (const int*)d_in[1];
    const int*  begins    = (const int*)d_in[2];
    const int*  ends      = (const int*)d_in[3];
    const float* mask     = (const float*)d_in[4];
    const float* Wbegin   = (const float*)d_in[5];
    const float* bbegin   = (const float*)d_in[6];
    const float* Wend     = (const float*)d_in[7];
    const float* bend     = (const float*)d_in[8];
    const float* Wmix3    = (const float*)d_in[9];
    const float* bmix3    = (const float*)d_in[10];
    const float* Wqkv     = (const float*)d_in[11];
    const float* bqkv     = (const float*)d_in[12];
    const float* wscore   = (const float*)d_in[13];
    const float* bscore   = (const float*)d_in[14];
    const float* Wout     = (const float*)d_in[15];
    const float* bout     = (const float*)d_in[16];
    const float* Wmix2    = (const float*)d_in[17];
    const float* bmix2    = (const float*)d_in[18];
    float* outp = (float*)d_out;

    char* ws = (char*)d_ws;
    bf16*  PK    = (bf16*)(ws + WS_PK);
    bf16*  Oatt  = (bf16*)(ws + WS_OATT);
    bf16*  OPS16 = (bf16*)(ws + WS_OPS16);
    float* sqf   = (float*)(ws + WS_SQF);
    float* skf   = (float*)(ws + WS_SKF);
    bf16*  G1T   = (bf16*)(ws + WS_G1T);
    bf16*  G2T   = (bf16*)(ws + WS_G2T);
    bf16*  G3T   = (bf16*)(ws + WS_G3T);
    bf16*  WCT   = (bf16*)(ws + WS_WCT);
    bf16*  GBT   = (bf16*)(ws + WS_GBT);
    bf16*  GET   = (bf16*)(ws + WS_GET);
    bf16*  WCN   = (bf16*)(ws + WS_WCN);
    bf16*  GBN   = (bf16*)(ws + WS_GBN);
    bf16*  GEN   = (bf16*)(ws + WS_GEN);
    bf16*  UQK   = (bf16*)(ws + WS_UQK);
    float* BBM   = (float*)(ws + WS_BBM);
    float* BBB   = (float*)(ws + WS_BBB);
    float* BBE   = (float*)(ws + WS_BBE);
    float* SC    = (float*)(ws + WS_SC);

    k_prepcast<<<dim3(1121), dim3(256), 0, stream>>>(
        ops, OPS16,
        Wmix3, Wmix2, Wout, Wbegin, Wend, Wqkv, bqkv, wscore, bscore,
        bmix3, bout, bmix2, bbegin, bend,
        G1T, G2T, G3T, WCT, GBT, GET, WCN, GBN, GEN,
        UQK, BBM, BBB, BBE, SC);

    k_v<<<dim3(128), dim3(256), 0, stream>>>(
        OPS16, Wqkv, bqkv, UQK, SC, PK, sqf, skf);

    k_att<<<dim3(512), dim3(256), 0, stream>>>(
        mask, PK, sqf, skf, Oatt);

    k_epi<<<dim3(520), dim3(256), 0, stream>>>(
        OPS16, relations, begins, ends, Oatt,
        G1T, G2T, G3T, WCT, GBN, GEN, WCN, BBM, BBB, BBE, outp);
}